// Round 4
// baseline (281.203 us; speedup 1.0000x reference)
//
#include <hip/hip_runtime.h>
#include <math.h>

// Fused self-attention layer (round 4).
// All matmuls on MFMA via split-bf16 (hi+lo): C = Ahi*Bhi + Ahi*Blo + Alo*Bhi,
// fp32 MFMA accumulation (~1e-6 rel err; bf16*bf16 exact in fp32).
// Attention: swapped QK^T (S^T = K*Q^T) so P^T is register-local for PV
// (B-operand slots coincide with the m89-verified C/D layout). Packing is
// layout-robust: A and B always share the same chosen k-map bijection, so
// correctness needs only (1) C/D layout col=lane&15,row=(lane>>4)*4+reg
// [HW-verified m89/m91] and (2) A/B operand-layout symmetry [same as GEMM].
//
// Workspace (72 MB): fp32 Q,K,V,Oscr,Y (40MB); bf16 Xhi,Xlo,Ohi,Olo (16MB);
// WThi,WTlo (16MB).

#define NTOK 2048
#define DM   1024
#define NH   16
#define HDIM 64

typedef __attribute__((ext_vector_type(8))) short bf16x8;
typedef __attribute__((ext_vector_type(4))) float f32x4;

__device__ __forceinline__ unsigned short f2bf(float f) {
  unsigned u = __float_as_uint(f);
  u += 0x7FFF + ((u >> 16) & 1);          // RNE
  return (unsigned short)(u >> 16);
}
__device__ __forceinline__ float bf2f(unsigned short h) {
  return __uint_as_float(((unsigned)h) << 16);
}

// ---------------------------------------------------------------------------
// Elementwise fp32 -> (bf16 hi, bf16 lo). n must be a multiple of 1024.
// ---------------------------------------------------------------------------
__global__ __launch_bounds__(256) void cvt_hilo_kernel(
    const float* __restrict__ in, unsigned short* __restrict__ hi,
    unsigned short* __restrict__ lo)
{
  const int i = (blockIdx.x * 256 + threadIdx.x) * 4;
  const float4 v = *(const float4*)(in + i);
  ushort4 h, l;
  h.x = f2bf(v.x); l.x = f2bf(v.x - bf2f(h.x));
  h.y = f2bf(v.y); l.y = f2bf(v.y - bf2f(h.y));
  h.z = f2bf(v.z); l.z = f2bf(v.z - bf2f(h.z));
  h.w = f2bf(v.w); l.w = f2bf(v.w - bf2f(h.w));
  *(ushort4*)(hi + i) = h;
  *(ushort4*)(lo + i) = l;
}

// ---------------------------------------------------------------------------
// Weight transpose + convert: W[K][N] fp32 -> WT hi/lo [N][K] bf16.
// ---------------------------------------------------------------------------
__global__ __launch_bounds__(256) void cvt_w_kernel(
    const float* __restrict__ W0, const float* __restrict__ W1,
    const float* __restrict__ W2, const float* __restrict__ W3,
    unsigned short* __restrict__ WThi, unsigned short* __restrict__ WTlo)
{
  __shared__ __align__(16) float st[64][68];
  const int z = blockIdx.z;
  const float* W = (z == 0) ? W0 : (z == 1) ? W1 : (z == 2) ? W2 : W3;
  const int k0 = blockIdx.y * 64, n0 = blockIdx.x * 64;
  const int tid = threadIdx.x;
  #pragma unroll
  for (int p = 0; p < 4; ++p) {
    const int row = p * 16 + (tid >> 4);
    const int c4  = (tid & 15) * 4;
    const float4 v = *(const float4*)(W + (size_t)(k0 + row) * DM + n0 + c4);
    *(float4*)&st[row][c4] = v;
  }
  __syncthreads();
  unsigned short* oh = WThi + (size_t)z * DM * DM;
  unsigned short* ol = WTlo + (size_t)z * DM * DM;
  #pragma unroll
  for (int p = 0; p < 4; ++p) {
    const int nl = p * 16 + (tid >> 4);
    const int k4 = (tid & 15) * 4;
    ushort4 h, l;
    float a = st[k4 + 0][nl]; h.x = f2bf(a); l.x = f2bf(a - bf2f(h.x));
    float b = st[k4 + 1][nl]; h.y = f2bf(b); l.y = f2bf(b - bf2f(h.y));
    float c = st[k4 + 2][nl]; h.z = f2bf(c); l.z = f2bf(c - bf2f(h.z));
    float d = st[k4 + 3][nl]; h.w = f2bf(d); l.w = f2bf(d - bf2f(h.w));
    *(ushort4*)(oh + (size_t)(n0 + nl) * DM + k0 + k4) = h;
    *(ushort4*)(ol + (size_t)(n0 + nl) * DM + k0 + k4) = l;
  }
}

// ---------------------------------------------------------------------------
// Split-bf16 MFMA GEMM core (unchanged from r3, desk-checked): C = A*B + bias
// [+residual]; A=[M][K] hi/lo, B transposed BT=[N][K] hi/lo. 64x64 tile,
// BK=64, 4 waves 2x2, each wave 32x32 (2x2 16x16x32 fragments).
// ---------------------------------------------------------------------------
__device__ __forceinline__ void gemm_mfma_core(
    const unsigned short* __restrict__ Ahi, const unsigned short* __restrict__ Alo,
    const unsigned short* __restrict__ BThi, const unsigned short* __restrict__ BTlo,
    const float* __restrict__ bias, const float* __restrict__ residual,
    float* __restrict__ C, int Nn, int K, unsigned short* lds)
{
  const int tid  = threadIdx.x;
  const int lane = tid & 63, wid = tid >> 6;
  const int wm = wid >> 1, wn = wid & 1;
  const int bm = blockIdx.y * 64, bn = blockIdx.x * 64;

  const int row_l = tid >> 2, j = tid & 3;
  const int g0   = 2 * (j & 1);
  const int eoff = (j >> 1) * 4;
  const int s_idx = row_l >> 4, lb = row_l & 15;

  const unsigned short* src[4];
  src[0] = Ahi  + (size_t)(bm + row_l) * K + 8 * j;
  src[1] = Alo  + (size_t)(bm + row_l) * K + 8 * j;
  src[2] = BThi + (size_t)(bn + row_l) * K + 8 * j;
  src[3] = BTlo + (size_t)(bn + row_l) * K + 8 * j;

  f32x4 acc[2][2];
  #pragma unroll
  for (int a = 0; a < 2; ++a)
    #pragma unroll
    for (int b = 0; b < 2; ++b)
      acc[a][b] = (f32x4){0.f, 0.f, 0.f, 0.f};

  for (int k0 = 0; k0 < K; k0 += 64) {
    __syncthreads();
    #pragma unroll
    for (int op = 0; op < 4; ++op) {
      #pragma unroll
      for (int c = 0; c < 2; ++c) {
        const uint4 v = *(const uint4*)(src[op] + k0 + 32 * c);
        const int base = ((op * 2 + c) * 4 + s_idx) * 64;
        *(uint2*)&lds[(size_t)(base + 16 * g0       + lb) * 8 + eoff] = make_uint2(v.x, v.y);
        *(uint2*)&lds[(size_t)(base + 16 * (g0 + 1) + lb) * 8 + eoff] = make_uint2(v.z, v.w);
      }
    }
    __syncthreads();
    #pragma unroll
    for (int c = 0; c < 2; ++c) {
      bf16x8 ah[2], al[2], bh[2], bl[2];
      #pragma unroll
      for (int f = 0; f < 2; ++f) {
        ah[f] = *(const bf16x8*)&lds[(size_t)(((0 * 2 + c) * 4 + 2 * wm + f) * 64 + lane) * 8];
        al[f] = *(const bf16x8*)&lds[(size_t)(((1 * 2 + c) * 4 + 2 * wm + f) * 64 + lane) * 8];
        bh[f] = *(const bf16x8*)&lds[(size_t)(((2 * 2 + c) * 4 + 2 * wn + f) * 64 + lane) * 8];
        bl[f] = *(const bf16x8*)&lds[(size_t)(((3 * 2 + c) * 4 + 2 * wn + f) * 64 + lane) * 8];
      }
      #pragma unroll
      for (int fm = 0; fm < 2; ++fm)
        #pragma unroll
        for (int fn = 0; fn < 2; ++fn) {
          acc[fm][fn] = __builtin_amdgcn_mfma_f32_16x16x32_bf16(ah[fm], bh[fn], acc[fm][fn], 0, 0, 0);
          acc[fm][fn] = __builtin_amdgcn_mfma_f32_16x16x32_bf16(ah[fm], bl[fn], acc[fm][fn], 0, 0, 0);
          acc[fm][fn] = __builtin_amdgcn_mfma_f32_16x16x32_bf16(al[fm], bh[fn], acc[fm][fn], 0, 0, 0);
        }
    }
  }

  const int r0 = bm + wm * 32, c0 = bn + wn * 32;
  #pragma unroll
  for (int fm = 0; fm < 2; ++fm)
    #pragma unroll
    for (int fn = 0; fn < 2; ++fn) {
      const int col  = c0 + fn * 16 + (lane & 15);
      const int rowb = r0 + fm * 16 + (lane >> 4) * 4;
      const float bcol = bias[col];
      #pragma unroll
      for (int r = 0; r < 4; ++r) {
        const int row = rowb + r;
        float v = acc[fm][fn][r] + bcol;
        if (residual) v += residual[(size_t)row * Nn + col];
        C[(size_t)row * Nn + col] = v;
      }
    }
}

__global__ __launch_bounds__(256) void gemm_qkv_mfma(
    const unsigned short* __restrict__ Xhi, const unsigned short* __restrict__ Xlo,
    const unsigned short* __restrict__ WThi, const unsigned short* __restrict__ WTlo,
    const float* __restrict__ bq, const float* __restrict__ bk,
    const float* __restrict__ bv,
    float* __restrict__ Q, float* __restrict__ K, float* __restrict__ V)
{
  __shared__ __align__(16) unsigned short lds[16384];
  const int z = blockIdx.z;
  const unsigned short* bth = WThi + (size_t)z * DM * DM;
  const unsigned short* btl = WTlo + (size_t)z * DM * DM;
  const float* bias = (z == 0) ? bq : (z == 1) ? bk : bv;
  float* C = (z == 0) ? Q : (z == 1) ? K : V;
  gemm_mfma_core(Xhi, Xlo, bth, btl, bias, nullptr, C, DM, DM, lds);
}

__global__ __launch_bounds__(256) void gemm_out_mfma(
    const unsigned short* __restrict__ Ohi, const unsigned short* __restrict__ Olo,
    const unsigned short* __restrict__ WThi, const unsigned short* __restrict__ WTlo,
    const float* __restrict__ bo, const float* __restrict__ X, float* __restrict__ Y)
{
  __shared__ __align__(16) unsigned short lds[16384];
  gemm_mfma_core(Ohi, Olo, WThi, WTlo, bo, X, Y, DM, DM, lds);
}

// ---------------------------------------------------------------------------
// MFMA flash attention, swapped QK^T. Block = (q-tile 64, head). 4 waves:
// wv0 = token-half (S^T rows), wv1 = q-half (S^T cols).
// S^T = K*Q^T per 64-token tile -> C-layout: lane(16g+c) holds
// S^T[32wv0+16fm+4g+r][32wv1+16fn+c]. Softmax per q-col: in-reg + shfl(16,32)
// + LDS exchange across the wv0 wave pair. P^T stays in registers as the PV
// B-operand (elem i: fm=i>>2, r=i&3). O^T = V^T*P^T accumulated per wave over
// its token half; cross-wave add at end; writes Oscr scrambled:
// Oscr[h*128 + 2*hd + (n>>10)][n&1023].
// ---------------------------------------------------------------------------
#define FR(op, ch, st, ln, e) (((((op) * 2 + (ch)) * 4 + (st)) * 64 + (ln)) * 8 + (e))

__global__ __launch_bounds__(256) void attn_mfma_kernel(
    const float* __restrict__ Q, const float* __restrict__ K,
    const float* __restrict__ V, float* __restrict__ Oscr)
{
  // ops: 0=Qhi 1=Qlo 2=Khi 3=Klo 4=Vhi(V^T) 5=Vlo(V^T); 48 KB
  __shared__ __align__(16) unsigned short frag[6 * 2 * 4 * 64 * 8];
  __shared__ float smax[2][64];
  __shared__ float ssum[2][64];

  const int tid  = threadIdx.x;
  const int lane = tid & 63;
  const int wid  = tid >> 6;
  const int wv0  = wid >> 1, wv1 = wid & 1;
  const int g    = lane >> 4, c = lane & 15;
  const int h    = blockIdx.y;
  const int q0   = blockIdx.x * 64;
  const int dbase = h * HDIM;

  const int row_l = tid >> 2, j = tid & 3;       // staging decomposition
  const int g0 = 2 * (j & 1), eoff = (j >> 1) * 4;
  const int st_i = row_l >> 4, lb = row_l & 15;

  // ---- Stage Q fragments once (ops 0,1): convert fp32->hi/lo inline.
  #pragma unroll
  for (int ch = 0; ch < 2; ++ch) {
    const float* srcp = Q + (size_t)(q0 + row_l) * DM + dbase + 32 * ch + 8 * j;
    const float4 a = *(const float4*)srcp;
    const float4 b = *(const float4*)(srcp + 4);
    const float vv[8] = {a.x, a.y, a.z, a.w, b.x, b.y, b.z, b.w};
    unsigned hi[8], lo[8];
    #pragma unroll
    for (int e = 0; e < 8; ++e) {
      hi[e] = f2bf(vv[e]);
      lo[e] = f2bf(vv[e] - bf2f((unsigned short)hi[e]));
    }
    *(uint2*)&frag[FR(0, ch, st_i, 16 * g0 + lb, eoff)]       = make_uint2(hi[0] | (hi[1] << 16), hi[2] | (hi[3] << 16));
    *(uint2*)&frag[FR(0, ch, st_i, 16 * (g0 + 1) + lb, eoff)] = make_uint2(hi[4] | (hi[5] << 16), hi[6] | (hi[7] << 16));
    *(uint2*)&frag[FR(1, ch, st_i, 16 * g0 + lb, eoff)]       = make_uint2(lo[0] | (lo[1] << 16), lo[2] | (lo[3] << 16));
    *(uint2*)&frag[FR(1, ch, st_i, 16 * (g0 + 1) + lb, eoff)] = make_uint2(lo[4] | (lo[5] << 16), lo[6] | (lo[7] << 16));
  }

  f32x4 acc_o[4][2];                              // [d-frag][q-frag] partial O^T
  #pragma unroll
  for (int df = 0; df < 4; ++df)
    #pragma unroll
    for (int fn = 0; fn < 2; ++fn)
      acc_o[df][fn] = (f32x4){0.f, 0.f, 0.f, 0.f};
  float m_run[2] = {-INFINITY, -INFINITY};
  float l_run[2] = {0.f, 0.f};

  for (int kt = 0; kt < NTOK / 64; ++kt) {
    const int k0t = kt * 64;
    __syncthreads();                              // A: prior PV/softmax reads done

    // ---- stage K (ops 2,3), same scatter as Q.
    #pragma unroll
    for (int ch = 0; ch < 2; ++ch) {
      const float* srcp = K + (size_t)(k0t + row_l) * DM + dbase + 32 * ch + 8 * j;
      const float4 a = *(const float4*)srcp;
      const float4 b = *(const float4*)(srcp + 4);
      const float vv[8] = {a.x, a.y, a.z, a.w, b.x, b.y, b.z, b.w};
      unsigned hi[8], lo[8];
      #pragma unroll
      for (int e = 0; e < 8; ++e) {
        hi[e] = f2bf(vv[e]);
        lo[e] = f2bf(vv[e] - bf2f((unsigned short)hi[e]));
      }
      *(uint2*)&frag[FR(2, ch, st_i, 16 * g0 + lb, eoff)]       = make_uint2(hi[0] | (hi[1] << 16), hi[2] | (hi[3] << 16));
      *(uint2*)&frag[FR(2, ch, st_i, 16 * (g0 + 1) + lb, eoff)] = make_uint2(hi[4] | (hi[5] << 16), hi[6] | (hi[7] << 16));
      *(uint2*)&frag[FR(3, ch, st_i, 16 * g0 + lb, eoff)]       = make_uint2(lo[0] | (lo[1] << 16), lo[2] | (lo[3] << 16));
      *(uint2*)&frag[FR(3, ch, st_i, 16 * (g0 + 1) + lb, eoff)] = make_uint2(lo[4] | (lo[5] << 16), lo[6] | (lo[7] << 16));
    }
    // ---- stage V^T (ops 4,5): wave wid loads tokens 16*wid..+16 at d=lane.
    {
      const int chv = wid >> 1, ihalf = wid & 1;  // token chunk, elem half
      float vals[16];
      #pragma unroll
      for (int tt = 0; tt < 16; ++tt)
        vals[tt] = V[(size_t)(k0t + 16 * wid + tt) * DM + dbase + lane];
      #pragma unroll
      for (int gg = 0; gg < 4; ++gg) {            // token sub-group (slot g)
        unsigned hi[4], lo[4];
        #pragma unroll
        for (int e = 0; e < 4; ++e) {
          hi[e] = f2bf(vals[4 * gg + e]);
          lo[e] = f2bf(vals[4 * gg + e] - bf2f((unsigned short)hi[e]));
        }
        *(uint2*)&frag[FR(4, chv, g, 16 * gg + c, 4 * ihalf)] = make_uint2(hi[0] | (hi[1] << 16), hi[2] | (hi[3] << 16));
        *(uint2*)&frag[FR(5, chv, g, 16 * gg + c, 4 * ihalf)] = make_uint2(lo[0] | (lo[1] << 16), lo[2] | (lo[3] << 16));
      }
    }
    __syncthreads();                              // B: staging visible

    // ---- S^T = K*Q^T (split 3-product)
    f32x4 sacc[2][2];
    #pragma unroll
    for (int fm = 0; fm < 2; ++fm)
      #pragma unroll
      for (int fn = 0; fn < 2; ++fn)
        sacc[fm][fn] = (f32x4){0.f, 0.f, 0.f, 0.f};
    #pragma unroll
    for (int ch = 0; ch < 2; ++ch) {
      bf16x8 kh[2], kl[2], qh[2], qlv[2];
      #pragma unroll
      for (int f = 0; f < 2; ++f) {
        kh[f]  = *(const bf16x8*)&frag[FR(2, ch, 2 * wv0 + f, lane, 0)];
        kl[f]  = *(const bf16x8*)&frag[FR(3, ch, 2 * wv0 + f, lane, 0)];
        qh[f]  = *(const bf16x8*)&frag[FR(0, ch, 2 * wv1 + f, lane, 0)];
        qlv[f] = *(const bf16x8*)&frag[FR(1, ch, 2 * wv1 + f, lane, 0)];
      }
      #pragma unroll
      for (int fm = 0; fm < 2; ++fm)
        #pragma unroll
        for (int fn = 0; fn < 2; ++fn) {
          sacc[fm][fn] = __builtin_amdgcn_mfma_f32_16x16x32_bf16(kh[fm], qh[fn],  sacc[fm][fn], 0, 0, 0);
          sacc[fm][fn] = __builtin_amdgcn_mfma_f32_16x16x32_bf16(kh[fm], qlv[fn], sacc[fm][fn], 0, 0, 0);
          sacc[fm][fn] = __builtin_amdgcn_mfma_f32_16x16x32_bf16(kl[fm], qh[fn],  sacc[fm][fn], 0, 0, 0);
        }
    }

    // ---- diagonal self-exclusion mask
    #pragma unroll
    for (int fm = 0; fm < 2; ++fm)
      #pragma unroll
      for (int fn = 0; fn < 2; ++fn)
        #pragma unroll
        for (int r = 0; r < 4; ++r) {
          const int tok = k0t + 32 * wv0 + 16 * fm + 4 * g + r;
          const int qq  = q0  + 32 * wv1 + 16 * fn + c;
          if (tok == qq) sacc[fm][fn][r] = -INFINITY;
        }

    // ---- per-q-col max over this wave's 32 tokens
    const int ql0 = 32 * wv1 + c;                 // q_local for fn=0 (+16 for fn=1)
    float mw[2];
    #pragma unroll
    for (int fn = 0; fn < 2; ++fn) {
      float m0 = fmaxf(fmaxf(sacc[0][fn][0], sacc[0][fn][1]),
                       fmaxf(sacc[0][fn][2], sacc[0][fn][3]));
      float m1 = fmaxf(fmaxf(sacc[1][fn][0], sacc[1][fn][1]),
                       fmaxf(sacc[1][fn][2], sacc[1][fn][3]));
      float m = fmaxf(m0, m1);
      m = fmaxf(m, __shfl_xor(m, 16, 64));
      m = fmaxf(m, __shfl_xor(m, 32, 64));
      mw[fn] = m;
    }
    if (g == 0) { smax[wv0][ql0] = mw[0]; smax[wv0][ql0 + 16] = mw[1]; }
    __syncthreads();                              // C: smax visible

    float mnew[2], scal[2], ps[2];
    #pragma unroll
    for (int fn = 0; fn < 2; ++fn) {
      const int ql = ql0 + 16 * fn;
      const float mtile = fmaxf(smax[0][ql], smax[1][ql]);
      mnew[fn] = fmaxf(m_run[fn], mtile);
      scal[fn] = __expf(m_run[fn] - mnew[fn]);    // first tile: exp(-inf)=0
      ps[fn] = 0.f;
    }
    #pragma unroll
    for (int fm = 0; fm < 2; ++fm)
      #pragma unroll
      for (int fn = 0; fn < 2; ++fn)
        #pragma unroll
        for (int r = 0; r < 4; ++r) {
          const float p = __expf(sacc[fm][fn][r] - mnew[fn]);  // masked -> 0
          sacc[fm][fn][r] = p;
          ps[fn] += p;
        }
    #pragma unroll
    for (int fn = 0; fn < 2; ++fn) {
      ps[fn] += __shfl_xor(ps[fn], 16, 64);
      ps[fn] += __shfl_xor(ps[fn], 32, 64);
    }
    if (g == 0) { ssum[wv0][ql0] = ps[0]; ssum[wv0][ql0 + 16] = ps[1]; }

    // ---- pack P^T -> bf16 hi/lo PV B-operand (elem i: fm=i>>2, r=i&3)
    bf16x8 ph[2], plo[2];
    #pragma unroll
    for (int fn = 0; fn < 2; ++fn)
      #pragma unroll
      for (int i = 0; i < 8; ++i) {
        const float pv = sacc[i >> 2][fn][i & 3];
        const unsigned short hp = f2bf(pv);
        ph[fn][i]  = (short)hp;
        plo[fn][i] = (short)f2bf(pv - bf2f(hp));
      }

    // ---- rescale partial O^T
    #pragma unroll
    for (int df = 0; df < 4; ++df)
      #pragma unroll
      for (int fn = 0; fn < 2; ++fn)
        #pragma unroll
        for (int r = 0; r < 4; ++r)
          acc_o[df][fn][r] *= scal[fn];

    __syncthreads();                              // D: ssum visible
    #pragma unroll
    for (int fn = 0; fn < 2; ++fn) {
      const int ql = ql0 + 16 * fn;
      l_run[fn] = l_run[fn] * scal[fn] + ssum[0][ql] + ssum[1][ql];
      m_run[fn] = mnew[fn];
    }

    // ---- PV: O^T += V^T(chunk=wv0) * P^T   (split 3-product)
    #pragma unroll
    for (int df = 0; df < 4; ++df) {
      const bf16x8 vh = *(const bf16x8*)&frag[FR(4, wv0, df, lane, 0)];
      const bf16x8 vl = *(const bf16x8*)&frag[FR(5, wv0, df, lane, 0)];
      #pragma unroll
      for (int fn = 0; fn < 2; ++fn) {
        acc_o[df][fn] = __builtin_amdgcn_mfma_f32_16x16x32_bf16(vh, ph[fn],  acc_o[df][fn], 0, 0, 0);
        acc_o[df][fn] = __builtin_amdgcn_mfma_f32_16x16x32_bf16(vh, plo[fn], acc_o[df][fn], 0, 0, 0);
        acc_o[df][fn] = __builtin_amdgcn_mfma_f32_16x16x32_bf16(vl, ph[fn],  acc_o[df][fn], 0, 0, 0);
      }
    }
  }

  // ---- cross-wave (wv0 pair) reduce via LDS overlay on dead K region
  float* redf = (float*)&frag[FR(2, 0, 0, 0, 0)];   // 16 KB, 16B-aligned
  __syncthreads();
  if (wv0 == 1) {
    #pragma unroll
    for (int df = 0; df < 4; ++df)
      #pragma unroll
      for (int fn = 0; fn < 2; ++fn)
        *(f32x4*)&redf[(((size_t)wv1 * 8 + df * 2 + fn) * 64 + lane) * 4] = acc_o[df][fn];
  }
  __syncthreads();
  if (wv0 == 0) {
    const int n1 = q0 >> 10, n0b = q0 & 1023;
    #pragma unroll
    for (int df = 0; df < 4; ++df)
      #pragma unroll
      for (int fn = 0; fn < 2; ++fn) {
        const f32x4 p = *(const f32x4*)&redf[(((size_t)wv1 * 8 + df * 2 + fn) * 64 + lane) * 4];
        const float inv = 1.0f / l_run[fn];
        const int q_local = 32 * wv1 + 16 * fn + c;
        #pragma unroll
        for (int r = 0; r < 4; ++r) {
          const int d = 16 * df + 4 * g + r;      // head-dim
          Oscr[(size_t)(h * 128 + 2 * d + n1) * DM + n0b + q_local] =
              (acc_o[df][fn][r] + p[r]) * inv;
        }
      }
  }
}

// ---------------------------------------------------------------------------
// LayerNorm (unchanged).
// ---------------------------------------------------------------------------
__global__ __launch_bounds__(256) void ln_kernel(
    const float* __restrict__ Y, const float* __restrict__ g,
    const float* __restrict__ b, float* __restrict__ out)
{
  __shared__ float red[8];
  const int row = blockIdx.x;
  const int tid = threadIdx.x;
  const float4 y = *(const float4*)(Y + (size_t)row * DM + tid * 4);
  float s  = y.x + y.y + y.z + y.w;
  float ss = y.x * y.x + y.y * y.y + y.z * y.z + y.w * y.w;
  #pragma unroll
  for (int o = 1; o < 64; o <<= 1) {
    s  += __shfl_xor(s, o, 64);
    ss += __shfl_xor(ss, o, 64);
  }
  const int wv = tid >> 6;
  if ((tid & 63) == 0) { red[wv] = s; red[4 + wv] = ss; }
  __syncthreads();
  s  = red[0] + red[1] + red[2] + red[3];
  ss = red[4] + red[5] + red[6] + red[7];
  const float mu   = s * (1.f / DM);
  const float var  = ss * (1.f / DM) - mu * mu;
  const float rstd = rsqrtf(var + 1e-5f);
  const float4 gv = *(const float4*)(g + tid * 4);
  const float4 bv = *(const float4*)(b + tid * 4);
  float4 o;
  o.x = (y.x - mu) * rstd * gv.x + bv.x;
  o.y = (y.y - mu) * rstd * gv.y + bv.y;
  o.z = (y.z - mu) * rstd * gv.z + bv.z;
  o.w = (y.w - mu) * rstd * gv.w + bv.w;
  *(float4*)(out + (size_t)row * DM + tid * 4) = o;
}

// ---------------------------------------------------------------------------
extern "C" void kernel_launch(void* const* d_in, const int* in_sizes, int n_in,
                              void* d_out, int out_size, void* d_ws, size_t ws_size,
                              hipStream_t stream) {
  const float* X    = (const float*)d_in[0];
  const float* Wq   = (const float*)d_in[1];
  const float* bq   = (const float*)d_in[2];
  const float* Wk   = (const float*)d_in[3];
  const float* bk   = (const float*)d_in[4];
  const float* Wv   = (const float*)d_in[5];
  const float* bv   = (const float*)d_in[6];
  const float* Wo   = (const float*)d_in[7];
  const float* bo   = (const float*)d_in[8];
  const float* ln_g = (const float*)d_in[9];
  const float* ln_b = (const float*)d_in[10];

  const size_t MAT = (size_t)NTOK * DM;   // 2,097,152
  float* ws   = (float*)d_ws;             // 72 MB total
  float* Q    = ws;
  float* Kp   = ws + MAT;
  float* Vp   = ws + 2 * MAT;
  float* Oscr = ws + 3 * MAT;
  float* Y    = ws + 4 * MAT;
  unsigned short* us = (unsigned short*)(ws + 5 * MAT);
  unsigned short* Xhi  = us;
  unsigned short* Xlo  = us + MAT;
  unsigned short* Ohi  = us + 2 * MAT;
  unsigned short* Olo  = us + 3 * MAT;
  unsigned short* WThi = us + 4 * MAT;    // 4 matrices of DM*DM
  unsigned short* WTlo = us + 6 * MAT;

  const dim3 blk(256);

  cvt_w_kernel<<<dim3(16, 16, 4), blk, 0, stream>>>(Wq, Wk, Wv, Wo, WThi, WTlo);
  cvt_hilo_kernel<<<dim3(MAT / 1024), blk, 0, stream>>>(X, Xhi, Xlo);

  gemm_qkv_mfma<<<dim3(DM / 64, NTOK / 64, 3), blk, 0, stream>>>(
      Xhi, Xlo, WThi, WTlo, bq, bk, bv, Q, Kp, Vp);

  attn_mfma_kernel<<<dim3(NTOK / 64, NH), blk, 0, stream>>>(Q, Kp, Vp, Oscr);

  cvt_hilo_kernel<<<dim3(MAT / 1024), blk, 0, stream>>>(Oscr, Ohi, Olo);

  gemm_out_mfma<<<dim3(DM / 64, NTOK / 64), blk, 0, stream>>>(
      Ohi, Olo, WThi + 3 * (size_t)DM * DM, WTlo + 3 * (size_t)DM * DM,
      bo, X, Y);

  ln_kernel<<<NTOK, blk, 0, stream>>>(Y, ln_g, ln_b, (float*)d_out);
}

// Round 5
// 236.343 us; speedup vs baseline: 1.1898x; 1.1898x over previous
//
#include <hip/hip_runtime.h>
#include <math.h>

// Fused self-attention layer (round 5).
// r4 counters: attn 129.6us VALU-bound (VALUBusy 58.5% vs MfmaUtil 16.6%,
// 4.26M LDS bank conflicts) -- inline fp32->bf16 hi/lo conversion of K/V per
// k-tile (redone by all 32 q-blocks) + scatter staging writes dominated.
// Fix: QKV GEMM epilogue emits Q/K/V as hi/lo bf16 fragment BLOBS (per
// head x 64-token tile, 16KB = exact LDS image). Attention stages them with
// global_load_lds (zero VALU, zero conflicts), double-buffered; each wave
// owns 16 q-cols over all 64 tokens -> softmax fully in-wave, ONE barrier
// per tile, no cross-wave exchange/reduce. Attn writes O as hi/lo bf16
// (deletes the Oscr fp32 + cvt pass).
//
// Split-bf16 everywhere: C = Ahi*Bhi + Ahi*Blo + Alo*Bhi (fp32 MFMA accum).
// Layout-robust fragment packing: A and B sides always share the same k-map
// bijection tau(g,e) = 4g + (e&3) + 16(e>>2); hard assumptions only:
//   C/D: col=lane&15, row=(lane>>4)*4+reg [HW-verified m89/m91]
//   A/B operand-layout symmetry [same as r3/r4, validated by r4 pass]
//
// Workspace (64 MB): Y fp32 (8MB); Xhi,Xlo,Ohi,Olo (16MB); WThi,WTlo (16MB);
// QF,KF,VF fragment blobs (24MB).

#define NTOK 2048
#define DM   1024
#define NH   16
#define HDIM 64

typedef __attribute__((ext_vector_type(8))) short bf16x8;
typedef __attribute__((ext_vector_type(4))) float f32x4;

// Fragment-slot index within one 16KB tile blob: [op(hi/lo)][ch][st][lane][e]
#define FRL(op, ch, st, l, e) (((((op) * 2 + (ch)) * 4 + (st)) * 64 + (l)) * 8 + (e))

__device__ __forceinline__ unsigned short f2bf(float f) {
  unsigned u = __float_as_uint(f);
  u += 0x7FFF + ((u >> 16) & 1);          // RNE
  return (unsigned short)(u >> 16);
}
__device__ __forceinline__ float bf2f(unsigned short h) {
  return __uint_as_float(((unsigned)h) << 16);
}

__device__ __forceinline__ void gload16(const unsigned short* g, unsigned short* l) {
  __builtin_amdgcn_global_load_lds(
      (const __attribute__((address_space(1))) unsigned int*)g,
      (__attribute__((address_space(3))) unsigned int*)l, 16, 0, 0);
}

// ---------------------------------------------------------------------------
// Elementwise fp32 -> (bf16 hi, bf16 lo).
// ---------------------------------------------------------------------------
__global__ __launch_bounds__(256) void cvt_hilo_kernel(
    const float* __restrict__ in, unsigned short* __restrict__ hi,
    unsigned short* __restrict__ lo)
{
  const int i = (blockIdx.x * 256 + threadIdx.x) * 4;
  const float4 v = *(const float4*)(in + i);
  ushort4 h, l;
  h.x = f2bf(v.x); l.x = f2bf(v.x - bf2f(h.x));
  h.y = f2bf(v.y); l.y = f2bf(v.y - bf2f(h.y));
  h.z = f2bf(v.z); l.z = f2bf(v.z - bf2f(h.z));
  h.w = f2bf(v.w); l.w = f2bf(v.w - bf2f(h.w));
  *(ushort4*)(hi + i) = h;
  *(ushort4*)(lo + i) = l;
}

// ---------------------------------------------------------------------------
// Weight transpose + convert: W[K][N] fp32 -> WT hi/lo [N][K] bf16.
// ---------------------------------------------------------------------------
__global__ __launch_bounds__(256) void cvt_w_kernel(
    const float* __restrict__ W0, const float* __restrict__ W1,
    const float* __restrict__ W2, const float* __restrict__ W3,
    unsigned short* __restrict__ WThi, unsigned short* __restrict__ WTlo)
{
  __shared__ __align__(16) float st[64][68];
  const int z = blockIdx.z;
  const float* W = (z == 0) ? W0 : (z == 1) ? W1 : (z == 2) ? W2 : W3;
  const int k0 = blockIdx.y * 64, n0 = blockIdx.x * 64;
  const int tid = threadIdx.x;
  #pragma unroll
  for (int p = 0; p < 4; ++p) {
    const int row = p * 16 + (tid >> 4);
    const int c4  = (tid & 15) * 4;
    const float4 v = *(const float4*)(W + (size_t)(k0 + row) * DM + n0 + c4);
    *(float4*)&st[row][c4] = v;
  }
  __syncthreads();
  unsigned short* oh = WThi + (size_t)z * DM * DM;
  unsigned short* ol = WTlo + (size_t)z * DM * DM;
  #pragma unroll
  for (int p = 0; p < 4; ++p) {
    const int nl = p * 16 + (tid >> 4);
    const int k4 = (tid & 15) * 4;
    ushort4 h, l;
    float a = st[k4 + 0][nl]; h.x = f2bf(a); l.x = f2bf(a - bf2f(h.x));
    float b = st[k4 + 1][nl]; h.y = f2bf(b); l.y = f2bf(b - bf2f(h.y));
    float c = st[k4 + 2][nl]; h.z = f2bf(c); l.z = f2bf(c - bf2f(h.z));
    float d = st[k4 + 3][nl]; h.w = f2bf(d); l.w = f2bf(d - bf2f(h.w));
    *(ushort4*)(oh + (size_t)(n0 + nl) * DM + k0 + k4) = h;
    *(ushort4*)(ol + (size_t)(n0 + nl) * DM + k0 + k4) = l;
  }
}

// ---------------------------------------------------------------------------
// Split-bf16 MFMA GEMM compute (main loop only; epilogue supplied by caller).
// A=[M][K] hi/lo, B transposed BT=[N][K] hi/lo. 64x64 tile, BK=64, 4 waves
// 2x2, each wave 32x32 (2x2 16x16x32 fragments). acc C-layout per thread:
// row = bm + wm*32 + fm*16 + (lane>>4)*4 + r, col = bn + wn*32 + fn*16 + (lane&15).
// ---------------------------------------------------------------------------
__device__ __forceinline__ void gemm_mfma_compute(
    const unsigned short* __restrict__ Ahi, const unsigned short* __restrict__ Alo,
    const unsigned short* __restrict__ BThi, const unsigned short* __restrict__ BTlo,
    int K, unsigned short* lds, f32x4 acc[2][2])
{
  const int tid  = threadIdx.x;
  const int lane = tid & 63, wid = tid >> 6;
  const int wm = wid >> 1, wn = wid & 1;
  const int bm = blockIdx.y * 64, bn = blockIdx.x * 64;

  const int row_l = tid >> 2, j = tid & 3;
  const int g0   = 2 * (j & 1);
  const int eoff = (j >> 1) * 4;
  const int s_idx = row_l >> 4, lb = row_l & 15;

  const unsigned short* src[4];
  src[0] = Ahi  + (size_t)(bm + row_l) * K + 8 * j;
  src[1] = Alo  + (size_t)(bm + row_l) * K + 8 * j;
  src[2] = BThi + (size_t)(bn + row_l) * K + 8 * j;
  src[3] = BTlo + (size_t)(bn + row_l) * K + 8 * j;

  #pragma unroll
  for (int a = 0; a < 2; ++a)
    #pragma unroll
    for (int b = 0; b < 2; ++b)
      acc[a][b] = (f32x4){0.f, 0.f, 0.f, 0.f};

  for (int k0 = 0; k0 < K; k0 += 64) {
    __syncthreads();
    #pragma unroll
    for (int op = 0; op < 4; ++op) {
      #pragma unroll
      for (int c = 0; c < 2; ++c) {
        const uint4 v = *(const uint4*)(src[op] + k0 + 32 * c);
        const int base = ((op * 2 + c) * 4 + s_idx) * 64;
        *(uint2*)&lds[(size_t)(base + 16 * g0       + lb) * 8 + eoff] = make_uint2(v.x, v.y);
        *(uint2*)&lds[(size_t)(base + 16 * (g0 + 1) + lb) * 8 + eoff] = make_uint2(v.z, v.w);
      }
    }
    __syncthreads();
    #pragma unroll
    for (int c = 0; c < 2; ++c) {
      bf16x8 ah[2], al[2], bh[2], bl[2];
      #pragma unroll
      for (int f = 0; f < 2; ++f) {
        ah[f] = *(const bf16x8*)&lds[(size_t)(((0 * 2 + c) * 4 + 2 * wm + f) * 64 + lane) * 8];
        al[f] = *(const bf16x8*)&lds[(size_t)(((1 * 2 + c) * 4 + 2 * wm + f) * 64 + lane) * 8];
        bh[f] = *(const bf16x8*)&lds[(size_t)(((2 * 2 + c) * 4 + 2 * wn + f) * 64 + lane) * 8];
        bl[f] = *(const bf16x8*)&lds[(size_t)(((3 * 2 + c) * 4 + 2 * wn + f) * 64 + lane) * 8];
      }
      #pragma unroll
      for (int fm = 0; fm < 2; ++fm)
        #pragma unroll
        for (int fn = 0; fn < 2; ++fn) {
          acc[fm][fn] = __builtin_amdgcn_mfma_f32_16x16x32_bf16(ah[fm], bh[fn], acc[fm][fn], 0, 0, 0);
          acc[fm][fn] = __builtin_amdgcn_mfma_f32_16x16x32_bf16(ah[fm], bl[fn], acc[fm][fn], 0, 0, 0);
          acc[fm][fn] = __builtin_amdgcn_mfma_f32_16x16x32_bf16(al[fm], bh[fn], acc[fm][fn], 0, 0, 0);
        }
    }
  }
}

// ---------------------------------------------------------------------------
// QKV GEMM: computes Q/K/V tile (64 tokens x 64 head-dims, head = blockIdx.x,
// token tile = blockIdx.y, z = matrix) and writes it as a 16KB hi/lo bf16
// fragment blob. Q,K token-major (S^T operands); V d-major (PV A-operand).
// ---------------------------------------------------------------------------
__global__ __launch_bounds__(256) void gemm_qkv_mfma(
    const unsigned short* __restrict__ Xhi, const unsigned short* __restrict__ Xlo,
    const unsigned short* __restrict__ WThi, const unsigned short* __restrict__ WTlo,
    const float* __restrict__ bq, const float* __restrict__ bk,
    const float* __restrict__ bv,
    unsigned short* __restrict__ QF, unsigned short* __restrict__ KF,
    unsigned short* __restrict__ VF)
{
  __shared__ __align__(16) unsigned short lds[16384];
  const int z = blockIdx.z;
  const unsigned short* bth = WThi + (size_t)z * DM * DM;
  const unsigned short* btl = WTlo + (size_t)z * DM * DM;
  const float* bias = (z == 0) ? bq : (z == 1) ? bk : bv;
  unsigned short* OUTF = (z == 0) ? QF : (z == 1) ? KF : VF;

  f32x4 acc[2][2];
  gemm_mfma_compute(Xhi, Xlo, bth, btl, DM, lds, acc);

  const int tid = threadIdx.x, lane = tid & 63, wid = tid >> 6;
  const int wm = wid >> 1, wn = wid & 1, g = lane >> 4, c = lane & 15;
  const int h = blockIdx.x, t = blockIdx.y;

  __syncthreads();                          // main-loop LDS reads complete
  #pragma unroll
  for (int fm = 0; fm < 2; ++fm)
    #pragma unroll
    for (int fn = 0; fn < 2; ++fn) {
      const float bcol = bias[h * 64 + wn * 32 + fn * 16 + c];
      #pragma unroll
      for (int r = 0; r < 4; ++r) {
        const float v = acc[fm][fn][r] + bcol;
        const unsigned short hp = f2bf(v);
        const unsigned short lp = f2bf(v - bf2f(hp));
        int ch, st, l, e;
        if (z != 2) {                       // token-major: rows = tokens
          ch = wn; st = 2 * wm + fm;
          l  = ((c >> 2) << 4) | (4 * g + r);
          e  = 4 * fn + (c & 3);
        } else {                            // d-major: rows = head-dims
          ch = wm; st = 2 * wn + fn;
          l  = (g << 4) | c;
          e  = 4 * fm + r;
        }
        lds[FRL(0, ch, st, l, e)] = hp;
        lds[FRL(1, ch, st, l, e)] = lp;
      }
    }
  __syncthreads();
  unsigned short* blob = OUTF + ((size_t)h * 32 + t) * 8192;
  #pragma unroll
  for (int s = 0; s < 4; ++s)
    *(uint4*)(blob + (size_t)(s * 256 + tid) * 8) =
        *(const uint4*)&lds[(size_t)(s * 256 + tid) * 8];
}

// ---------------------------------------------------------------------------
// Out-proj GEMM: Y = O @ Wo + bo + X (fp32 epilogue, unchanged).
// ---------------------------------------------------------------------------
__global__ __launch_bounds__(256) void gemm_out_mfma(
    const unsigned short* __restrict__ Ohi, const unsigned short* __restrict__ Olo,
    const unsigned short* __restrict__ WThi, const unsigned short* __restrict__ WTlo,
    const float* __restrict__ bo, const float* __restrict__ X, float* __restrict__ Y)
{
  __shared__ __align__(16) unsigned short lds[16384];
  f32x4 acc[2][2];
  gemm_mfma_compute(Ohi, Olo, WThi, WTlo, DM, lds, acc);

  const int tid = threadIdx.x, lane = tid & 63, wid = tid >> 6;
  const int wm = wid >> 1, wn = wid & 1;
  const int bm = blockIdx.y * 64, bn = blockIdx.x * 64;
  const int r0 = bm + wm * 32, c0 = bn + wn * 32;
  #pragma unroll
  for (int fm = 0; fm < 2; ++fm)
    #pragma unroll
    for (int fn = 0; fn < 2; ++fn) {
      const int col  = c0 + fn * 16 + (lane & 15);
      const int rowb = r0 + fm * 16 + (lane >> 4) * 4;
      const float bcol = bo[col];
      #pragma unroll
      for (int r = 0; r < 4; ++r) {
        const int row = rowb + r;
        Y[(size_t)row * DM + col] =
            acc[fm][fn][r] + bcol + X[(size_t)row * DM + col];
      }
    }
}

// ---------------------------------------------------------------------------
// MFMA flash attention v2. Block = (q-tile 64, head); 4 waves, wave wv owns
// q-cols 16*wv..16*wv+15 over ALL 64 tokens of each k-tile: softmax is fully
// in-wave (in-reg + shfl_xor 16/32), no cross-wave exchange, no final reduce.
// K/V staged from fragment blobs via global_load_lds, double-buffered, ONE
// __syncthreads per tile (its vmcnt-drain completes the prefetch). Writes
// O scrambled as hi/lo bf16: row h*128+2*hd+(n>>10), col n&1023.
// ---------------------------------------------------------------------------
__global__ __launch_bounds__(256) void attn_mfma2_kernel(
    const unsigned short* __restrict__ QF, const unsigned short* __restrict__ KF,
    const unsigned short* __restrict__ VF,
    unsigned short* __restrict__ Ohi, unsigned short* __restrict__ Olo)
{
  __shared__ __align__(16) unsigned short lds[32768];  // [2 buf][K 8192 | V 8192]

  const int tid = threadIdx.x, lane = tid & 63, wv = tid >> 6;
  const int g = lane >> 4, c = lane & 15;
  const int h = blockIdx.y, tq = blockIdx.x;
  const int q0 = tq * 64;
  const int qq = q0 + 16 * wv + c;          // this thread's q column

  // Q fragments (stripe = wv) -> registers, once.
  const unsigned short* qb = QF + ((size_t)h * 32 + tq) * 8192;
  bf16x8 qh[2], ql[2];
  #pragma unroll
  for (int ch = 0; ch < 2; ++ch) {
    qh[ch] = *(const bf16x8*)(qb + FRL(0, ch, wv, lane, 0));
    ql[ch] = *(const bf16x8*)(qb + FRL(1, ch, wv, lane, 0));
  }

  f32x4 acc_o[4];
  #pragma unroll
  for (int df = 0; df < 4; ++df) acc_o[df] = (f32x4){0.f, 0.f, 0.f, 0.f};
  float m_run = -INFINITY, l_run = 0.f;

  const size_t hbase = (size_t)h * 32;
  // Prologue: stage tile 0 into buffer 0.
  {
    const unsigned short* kb = KF + (hbase + 0) * 8192;
    const unsigned short* vb = VF + (hbase + 0) * 8192;
    #pragma unroll
    for (int s = 0; s < 4; ++s) {
      gload16(kb + (size_t)(s * 256 + tid) * 8, &lds[(size_t)(s * 256 + tid) * 8]);
      gload16(vb + (size_t)(s * 256 + tid) * 8, &lds[8192 + (size_t)(s * 256 + tid) * 8]);
    }
  }

  int buf = 0;
  for (int kt = 0; kt < NTOK / 64; ++kt) {
    __syncthreads();  // drains vmcnt -> buf ready; all waves done with buf^1
    if (kt + 1 < NTOK / 64) {               // prefetch next tile into buf^1
      const unsigned short* kb = KF + (hbase + kt + 1) * 8192;
      const unsigned short* vb = VF + (hbase + kt + 1) * 8192;
      unsigned short* lk = &lds[(buf ^ 1) * 16384];
      #pragma unroll
      for (int s = 0; s < 4; ++s) {
        gload16(kb + (size_t)(s * 256 + tid) * 8, lk + (size_t)(s * 256 + tid) * 8);
        gload16(vb + (size_t)(s * 256 + tid) * 8, lk + 8192 + (size_t)(s * 256 + tid) * 8);
      }
    }
    const unsigned short* lk = &lds[buf * 16384];
    const unsigned short* lv = lk + 8192;

    // ---- S^T = K * Q^T (split 3-product). Thread: tokens 16fm+4g+r, q col qq.
    f32x4 sacc[4];
    #pragma unroll
    for (int fm = 0; fm < 4; ++fm) sacc[fm] = (f32x4){0.f, 0.f, 0.f, 0.f};
    #pragma unroll
    for (int ch = 0; ch < 2; ++ch) {
      #pragma unroll
      for (int fm = 0; fm < 4; ++fm) {
        const bf16x8 khf = *(const bf16x8*)&lk[FRL(0, ch, fm, lane, 0)];
        const bf16x8 klf = *(const bf16x8*)&lk[FRL(1, ch, fm, lane, 0)];
        sacc[fm] = __builtin_amdgcn_mfma_f32_16x16x32_bf16(khf, qh[ch], sacc[fm], 0, 0, 0);
        sacc[fm] = __builtin_amdgcn_mfma_f32_16x16x32_bf16(khf, ql[ch], sacc[fm], 0, 0, 0);
        sacc[fm] = __builtin_amdgcn_mfma_f32_16x16x32_bf16(klf, qh[ch], sacc[fm], 0, 0, 0);
      }
    }

    // ---- diagonal mask + online softmax (in-wave: lanes {c,c+16,c+32,c+48})
    const int tok0 = kt * 64 + 4 * g;
    #pragma unroll
    for (int fm = 0; fm < 4; ++fm)
      #pragma unroll
      for (int r = 0; r < 4; ++r)
        if (tok0 + 16 * fm + r == qq) sacc[fm][r] = -INFINITY;

    float m = -INFINITY;
    #pragma unroll
    for (int fm = 0; fm < 4; ++fm)
      #pragma unroll
      for (int r = 0; r < 4; ++r) m = fmaxf(m, sacc[fm][r]);
    m = fmaxf(m, __shfl_xor(m, 16, 64));
    m = fmaxf(m, __shfl_xor(m, 32, 64));
    const float mnew = fmaxf(m_run, m);
    const float scal = __expf(m_run - mnew);   // first tile: exp(-inf)=0
    float ps = 0.f;
    #pragma unroll
    for (int fm = 0; fm < 4; ++fm)
      #pragma unroll
      for (int r = 0; r < 4; ++r) {
        const float p = __expf(sacc[fm][r] - mnew);
        sacc[fm][r] = p;
        ps += p;
      }
    ps += __shfl_xor(ps, 16, 64);
    ps += __shfl_xor(ps, 32, 64);
    l_run = l_run * scal + ps;
    m_run = mnew;

    // ---- pack P -> hi/lo bf16 PV B-operand: pb[ch][i] = sacc[2ch+(i>>2)][i&3]
    bf16x8 ph[2], pl[2];
    #pragma unroll
    for (int ch = 0; ch < 2; ++ch)
      #pragma unroll
      for (int i = 0; i < 8; ++i) {
        const float pv = sacc[2 * ch + (i >> 2)][i & 3];
        const unsigned short hp = f2bf(pv);
        ph[ch][i] = (short)hp;
        pl[ch][i] = (short)f2bf(pv - bf2f(hp));
      }

    // ---- rescale partial O, then PV: O^T += V^T * P^T (split 3-product)
    #pragma unroll
    for (int df = 0; df < 4; ++df)
      #pragma unroll
      for (int r = 0; r < 4; ++r) acc_o[df][r] *= scal;
    #pragma unroll
    for (int ch = 0; ch < 2; ++ch)
      #pragma unroll
      for (int df = 0; df < 4; ++df) {
        const bf16x8 vh = *(const bf16x8*)&lv[FRL(0, ch, df, lane, 0)];
        const bf16x8 vl = *(const bf16x8*)&lv[FRL(1, ch, df, lane, 0)];
        acc_o[df] = __builtin_amdgcn_mfma_f32_16x16x32_bf16(vh, ph[ch], acc_o[df], 0, 0, 0);
        acc_o[df] = __builtin_amdgcn_mfma_f32_16x16x32_bf16(vh, pl[ch], acc_o[df], 0, 0, 0);
        acc_o[df] = __builtin_amdgcn_mfma_f32_16x16x32_bf16(vl, ph[ch], acc_o[df], 0, 0, 0);
      }
    buf ^= 1;
  }

  // ---- epilogue: normalize, write O scrambled as hi/lo bf16
  const float inv = 1.0f / l_run;
  const int colo = (q0 & 1023) + 16 * wv + c;
  const int rowb = h * 128 + (q0 >> 10);
  #pragma unroll
  for (int df = 0; df < 4; ++df)
    #pragma unroll
    for (int r = 0; r < 4; ++r) {
      const int d = 16 * df + 4 * g + r;
      const float val = acc_o[df][r] * inv;
      const unsigned short hp = f2bf(val);
      const size_t off = (size_t)(rowb + 2 * d) * DM + colo;
      Ohi[off] = hp;
      Olo[off] = f2bf(val - bf2f(hp));
    }
}

// ---------------------------------------------------------------------------
// LayerNorm (unchanged).
// ---------------------------------------------------------------------------
__global__ __launch_bounds__(256) void ln_kernel(
    const float* __restrict__ Y, const float* __restrict__ g,
    const float* __restrict__ b, float* __restrict__ out)
{
  __shared__ float red[8];
  const int row = blockIdx.x;
  const int tid = threadIdx.x;
  const float4 y = *(const float4*)(Y + (size_t)row * DM + tid * 4);
  float s  = y.x + y.y + y.z + y.w;
  float ss = y.x * y.x + y.y * y.y + y.z * y.z + y.w * y.w;
  #pragma unroll
  for (int o = 1; o < 64; o <<= 1) {
    s  += __shfl_xor(s, o, 64);
    ss += __shfl_xor(ss, o, 64);
  }
  const int wv = tid >> 6;
  if ((tid & 63) == 0) { red[wv] = s; red[4 + wv] = ss; }
  __syncthreads();
  s  = red[0] + red[1] + red[2] + red[3];
  ss = red[4] + red[5] + red[6] + red[7];
  const float mu   = s * (1.f / DM);
  const float var  = ss * (1.f / DM) - mu * mu;
  const float rstd = rsqrtf(var + 1e-5f);
  const float4 gv = *(const float4*)(g + tid * 4);
  const float4 bv = *(const float4*)(b + tid * 4);
  float4 o;
  o.x = (y.x - mu) * rstd * gv.x + bv.x;
  o.y = (y.y - mu) * rstd * gv.y + bv.y;
  o.z = (y.z - mu) * rstd * gv.z + bv.z;
  o.w = (y.w - mu) * rstd * gv.w + bv.w;
  *(float4*)(out + (size_t)row * DM + tid * 4) = o;
}

// ---------------------------------------------------------------------------
extern "C" void kernel_launch(void* const* d_in, const int* in_sizes, int n_in,
                              void* d_out, int out_size, void* d_ws, size_t ws_size,
                              hipStream_t stream) {
  const float* X    = (const float*)d_in[0];
  const float* Wq   = (const float*)d_in[1];
  const float* bq   = (const float*)d_in[2];
  const float* Wk   = (const float*)d_in[3];
  const float* bk   = (const float*)d_in[4];
  const float* Wv   = (const float*)d_in[5];
  const float* bv   = (const float*)d_in[6];
  const float* Wo   = (const float*)d_in[7];
  const float* bo   = (const float*)d_in[8];
  const float* ln_g = (const float*)d_in[9];
  const float* ln_b = (const float*)d_in[10];

  const size_t MAT = (size_t)NTOK * DM;     // 2,097,152
  float* Y = (float*)d_ws;                  // 8 MB
  unsigned short* us = (unsigned short*)(Y + MAT);
  unsigned short* Xhi  = us;                // 1 MAT-unit each (4 MB)
  unsigned short* Xlo  = Xhi + MAT;
  unsigned short* Ohi  = Xlo + MAT;
  unsigned short* Olo  = Ohi + MAT;
  unsigned short* WThi = Olo + MAT;         // 2 MAT-units (4 matrices)
  unsigned short* WTlo = WThi + 2 * MAT;
  unsigned short* QF   = WTlo + 2 * MAT;    // 2 MAT-units each (16*32*8192)
  unsigned short* KF   = QF + 2 * MAT;
  unsigned short* VF   = KF + 2 * MAT;      // total 64 MB

  const dim3 blk(256);

  cvt_w_kernel<<<dim3(16, 16, 4), blk, 0, stream>>>(Wq, Wk, Wv, Wo, WThi, WTlo);
  cvt_hilo_kernel<<<dim3(MAT / 1024), blk, 0, stream>>>(X, Xhi, Xlo);

  gemm_qkv_mfma<<<dim3(DM / 64, NTOK / 64, 3), blk, 0, stream>>>(
      Xhi, Xlo, WThi, WTlo, bq, bk, bv, QF, KF, VF);

  attn_mfma2_kernel<<<dim3(NTOK / 64, NH), blk, 0, stream>>>(QF, KF, VF, Ohi, Olo);

  gemm_out_mfma<<<dim3(DM / 64, NTOK / 64), blk, 0, stream>>>(
      Ohi, Olo, WThi + 3 * (size_t)DM * DM, WTlo + 3 * (size_t)DM * DM,
      bo, X, Y);

  ln_kernel<<<NTOK, blk, 0, stream>>>(Y, ln_g, ln_b, (float*)d_out);
}

// Round 7
// 228.362 us; speedup vs baseline: 1.2314x; 1.0349x over previous
//
#include <hip/hip_runtime.h>
#include <math.h>

// Fused self-attention layer (round 7 = round 6 + staging-offset fix).
// r6 FAILED (absmax 4.5): gemm_out_blob staged A/B at wrong LDS offsets
// (O blobs are 4096 shorts = 512 units, not 256; Wo blobs belong at unit
// 1024/2048, code placed them at 512/1536 and staged only half of each O
// blob). Fix: A = 2x512 units at [0,1024); B = 2x1024 units at [1024,3072).
// All other r6 structures unchanged (desk-checked):
//  - 128^2-tile m97-class GEMMs on pre-packed hi/lo bf16 fragment blobs
//    (global_load_lds staging, lane-linear ds_read_b128, 0 bank conflicts)
//  - attention: exp2-domain softmax (Q pre-scaled by log2e), P-lo dropped
//    (P in [0,1], 2^-9 rel), hi-only O blobs (out-proj 2-product), setprio.
//
// Blob format: 64x64 tile, FRL(op,ch,st,lane,e): row = 16*st + (lane&15),
// k = 32*ch + tau(lane>>4,e), tau(g,e) = 4g + (e&3) + 16(e>>2). A and B
// always share tau -> result invariant to the true HW k-map. Hard
// assumptions only: C/D col=lane&15,row=(lane>>4)*4+reg [m89/m91]; A/B
// operand-layout symmetry [validated r4/r5/r6-qkv pass].
//
// Workspace (60MB): Y fp32 8MB | XB 8MB | WB 16MB | QF/KF/VF 24MB | OF 4MB.

#define NTOK 2048
#define DM   1024
#define NH   16
#define HDIM 64
#define LOG2E 1.4426950408889634f

typedef __attribute__((ext_vector_type(8))) short bf16x8;
typedef __attribute__((ext_vector_type(4))) float f32x4;

// hi/lo blob slot (8192 shorts): [op][ch][st][lane][e]
#define FRL(op, ch, st, l, e) (((((op) * 2 + (ch)) * 4 + (st)) * 64 + (l)) * 8 + (e))
// hi-only blob slot (4096 shorts): [ch][st][lane][e]
#define FRO(ch, st, l, e) ((((ch) * 4 + (st)) * 64 + (l)) * 8 + (e))
#define MFMA(a, b, c) __builtin_amdgcn_mfma_f32_16x16x32_bf16(a, b, c, 0, 0, 0)

__device__ __forceinline__ unsigned short f2bf(float f) {
  unsigned u = __float_as_uint(f);
  u += 0x7FFF + ((u >> 16) & 1);          // RNE
  return (unsigned short)(u >> 16);
}
__device__ __forceinline__ float bf2f(unsigned short h) {
  return __uint_as_float(((unsigned)h) << 16);
}
__device__ __forceinline__ void gload16(const unsigned short* g, unsigned short* l) {
  __builtin_amdgcn_global_load_lds(
      (const __attribute__((address_space(1))) unsigned int*)g,
      (__attribute__((address_space(3))) unsigned int*)l, 16, 0, 0);
}

// ---------------------------------------------------------------------------
// X [2048][1024] fp32 -> hi/lo blobs XB[(rt*16+kt)*8192]. One block per blob.
// ---------------------------------------------------------------------------
__global__ __launch_bounds__(256) void cvt_x_blob(
    const float* __restrict__ X, unsigned short* __restrict__ XB)
{
  __shared__ __align__(16) unsigned short img[8192];
  const int kt = blockIdx.x, rt = blockIdx.y, tid = threadIdx.x;
  #pragma unroll
  for (int s = 0; s < 4; ++s) {
    const int f = tid + s * 256;
    const int rl = f >> 4, c4 = (f & 15) * 4;
    const float4 v = *(const float4*)(X + (size_t)(rt * 64 + rl) * DM + kt * 64 + c4);
    const float vv[4] = {v.x, v.y, v.z, v.w};
    unsigned short hi[4], lo[4];
    #pragma unroll
    for (int e = 0; e < 4; ++e) {
      hi[e] = f2bf(vv[e]);
      lo[e] = f2bf(vv[e] - bf2f(hi[e]));
    }
    const int ch = c4 >> 5, c32 = c4 & 31;
    const int gp = (c32 & 15) >> 2, e0 = (c32 >> 4) * 4;
    const int l = 16 * gp + (rl & 15), sti = rl >> 4;
    *(uint2*)&img[FRL(0, ch, sti, l, e0)] =
        make_uint2(hi[0] | (hi[1] << 16), hi[2] | (hi[3] << 16));
    *(uint2*)&img[FRL(1, ch, sti, l, e0)] =
        make_uint2(lo[0] | (lo[1] << 16), lo[2] | (lo[3] << 16));
  }
  __syncthreads();
  unsigned short* out = XB + ((size_t)rt * 16 + kt) * 8192;
  #pragma unroll
  for (int s = 0; s < 4; ++s) {
    const int u = s * 256 + tid;
    *(uint4*)(out + (size_t)u * 8) = *(const uint4*)&img[(size_t)u * 8];
  }
}

// ---------------------------------------------------------------------------
// W [K][N] fp32 -> transposed hi/lo blobs (rows=n, k=k) at WB + z*2097152.
// ---------------------------------------------------------------------------
__global__ __launch_bounds__(256) void cvt_w_blob(
    const float* __restrict__ W0, const float* __restrict__ W1,
    const float* __restrict__ W2, const float* __restrict__ W3,
    unsigned short* __restrict__ WB)
{
  __shared__ __align__(16) float st[64][68];
  __shared__ __align__(16) unsigned short img[8192];
  const int nt = blockIdx.x, kt = blockIdx.y, z = blockIdx.z, tid = threadIdx.x;
  const float* W = (z == 0) ? W0 : (z == 1) ? W1 : (z == 2) ? W2 : W3;
  #pragma unroll
  for (int s = 0; s < 4; ++s) {
    const int f = tid + s * 256;
    const int kl = f >> 4, n4 = (f & 15) * 4;
    const float4 v = *(const float4*)(W + (size_t)(kt * 64 + kl) * DM + nt * 64 + n4);
    *(float4*)&st[kl][n4] = v;
  }
  __syncthreads();
  #pragma unroll
  for (int s = 0; s < 4; ++s) {
    const int f = tid + s * 256;
    const int nl = f >> 4, k4 = (f & 15) * 4;
    unsigned short hi[4], lo[4];
    #pragma unroll
    for (int e = 0; e < 4; ++e) {
      const float v = st[k4 + e][nl];
      hi[e] = f2bf(v);
      lo[e] = f2bf(v - bf2f(hi[e]));
    }
    const int ch = k4 >> 5, c32 = k4 & 31;
    const int gp = (c32 & 15) >> 2, e0 = (c32 >> 4) * 4;
    const int l = 16 * gp + (nl & 15), sti = nl >> 4;
    *(uint2*)&img[FRL(0, ch, sti, l, e0)] =
        make_uint2(hi[0] | (hi[1] << 16), hi[2] | (hi[3] << 16));
    *(uint2*)&img[FRL(1, ch, sti, l, e0)] =
        make_uint2(lo[0] | (lo[1] << 16), lo[2] | (lo[3] << 16));
  }
  __syncthreads();
  unsigned short* out = WB + (size_t)z * 2097152 + ((size_t)nt * 16 + kt) * 8192;
  #pragma unroll
  for (int s = 0; s < 4; ++s) {
    const int u = s * 256 + tid;
    *(uint4*)(out + (size_t)u * 8) = *(const uint4*)&img[(size_t)u * 8];
  }
}

// ---------------------------------------------------------------------------
// QKV GEMM, 128x128 tile, BK=64, m97 2-barrier loop, split-bf16 3-product.
// Epilogue emits Q/K (token-major, Q pre-scaled by log2e) / V (d-major)
// hi/lo fragment blobs for the attention kernel.
// ---------------------------------------------------------------------------
__global__ __launch_bounds__(256) void gemm_qkv_blob(
    const unsigned short* __restrict__ XB, const unsigned short* __restrict__ WB,
    const float* __restrict__ bq, const float* __restrict__ bk,
    const float* __restrict__ bv,
    unsigned short* __restrict__ QF, unsigned short* __restrict__ KF,
    unsigned short* __restrict__ VF)
{
  __shared__ __align__(16) unsigned short lds[32768];  // 64KB: A(2 blobs)|B(2 blobs)
  const int tid = threadIdx.x, lane = tid & 63, wid = tid >> 6;
  const int wm = wid >> 1, wn = wid & 1;
  const int bx = blockIdx.x, by = blockIdx.y, z = blockIdx.z;
  const int g = lane >> 4, c = lane & 15;

  const unsigned short* BB = WB + (size_t)z * 2097152;
  const unsigned short* bases[4] = {
      XB + ((size_t)(2 * by) * 16) * 8192, XB + ((size_t)(2 * by + 1) * 16) * 8192,
      BB + ((size_t)(2 * bx) * 16) * 8192, BB + ((size_t)(2 * bx + 1) * 16) * 8192};

  f32x4 acc[4][4];
  #pragma unroll
  for (int i = 0; i < 4; ++i)
    #pragma unroll
    for (int j = 0; j < 4; ++j) acc[i][j] = (f32x4){0.f, 0.f, 0.f, 0.f};

  for (int kt = 0; kt < 16; ++kt) {
    __syncthreads();
    #pragma unroll
    for (int s = 0; s < 16; ++s)
      gload16(bases[s >> 2] + (size_t)kt * 8192 + ((size_t)((s & 3) * 256 + tid)) * 8,
              &lds[(size_t)(s * 256 + tid) * 8]);
    __syncthreads();
    #pragma unroll
    for (int ch = 0; ch < 2; ++ch) {
      bf16x8 ah[4], al[4], bh[4], bl[4];
      #pragma unroll
      for (int f = 0; f < 4; ++f) {
        ah[f] = *(const bf16x8*)&lds[wm * 8192 + FRL(0, ch, f, lane, 0)];
        al[f] = *(const bf16x8*)&lds[wm * 8192 + FRL(1, ch, f, lane, 0)];
        bh[f] = *(const bf16x8*)&lds[16384 + wn * 8192 + FRL(0, ch, f, lane, 0)];
        bl[f] = *(const bf16x8*)&lds[16384 + wn * 8192 + FRL(1, ch, f, lane, 0)];
      }
      #pragma unroll
      for (int fm = 0; fm < 4; ++fm)
        #pragma unroll
        for (int fn = 0; fn < 4; ++fn) {
          acc[fm][fn] = MFMA(ah[fm], bh[fn], acc[fm][fn]);
          acc[fm][fn] = MFMA(ah[fm], bl[fn], acc[fm][fn]);
          acc[fm][fn] = MFMA(al[fm], bh[fn], acc[fm][fn]);
        }
    }
  }

  const float* bias = (z == 0) ? bq : (z == 1) ? bk : bv;
  unsigned short* OUTF = (z == 0) ? QF : (z == 1) ? KF : VF;

  __syncthreads();                         // main-loop LDS reads complete
  const int imgb = (wm * 2 + wn) * 8192;   // this wave's blob image quadrant
  #pragma unroll
  for (int fm = 0; fm < 4; ++fm)
    #pragma unroll
    for (int fn = 0; fn < 4; ++fn) {
      const int col = 128 * bx + 64 * wn + 16 * fn + c;
      const float bcol = bias[col];
      #pragma unroll
      for (int r = 0; r < 4; ++r) {
        float val = acc[fm][fn][r] + bcol;
        if (z == 0) val *= LOG2E;          // exp2-domain softmax
        const unsigned short hp = f2bf(val);
        const unsigned short lp = f2bf(val - bf2f(hp));
        int sti, l, ch_i, e;
        if (z != 2) {                      // token-major (rows = tokens)
          sti = fm; l = 16 * (c >> 2) + (4 * g + r);
          ch_i = fn >> 1; e = 4 * (fn & 1) + (c & 3);
        } else {                           // d-major (rows = head-dims)
          sti = fn; l = 16 * g + c;
          ch_i = fm >> 1; e = 4 * (fm & 1) + r;
        }
        lds[imgb + FRL(0, ch_i, sti, l, e)] = hp;
        lds[imgb + FRL(1, ch_i, sti, l, e)] = lp;
      }
    }
  __syncthreads();
  #pragma unroll
  for (int s = 0; s < 16; ++s) {
    const int u = s * 256 + tid;
    const int i = s >> 2;                  // image quadrant (wm_i*2 + wn_i)
    const int head = 2 * bx + (i & 1), tt = 2 * by + (i >> 1);
    *(uint4*)(OUTF + ((size_t)head * 32 + tt) * 8192 + (size_t)(u & 1023) * 8) =
        *(const uint4*)&lds[(size_t)u * 8];
  }
}

// ---------------------------------------------------------------------------
// Out-proj GEMM: Y = O @ Wo + bo + X. A = hi-only O blobs (2-product),
// B = Wo hi/lo blobs. 128x128 tile, BK=64.
// LDS unit map (16B units): A0 [0,512) | A1 [512,1024) | B0 [1024,2048) |
// B1 [2048,3072)  -> shorts: A0 @0, A1 @4096, B0 @8192, B1 @16384.
// ---------------------------------------------------------------------------
__global__ __launch_bounds__(256) void gemm_out_blob(
    const unsigned short* __restrict__ OF, const unsigned short* __restrict__ WoB,
    const float* __restrict__ bo, const float* __restrict__ X,
    float* __restrict__ Y)
{
  __shared__ __align__(16) unsigned short lds[24576];  // 48KB
  const int tid = threadIdx.x, lane = tid & 63, wid = tid >> 6;
  const int wm = wid >> 1, wn = wid & 1;
  const int bx = blockIdx.x, by = blockIdx.y;

  const unsigned short* oa0 = OF + ((size_t)(2 * by) * 16) * 4096;
  const unsigned short* oa1 = OF + ((size_t)(2 * by + 1) * 16) * 4096;
  const unsigned short* wb0 = WoB + ((size_t)(2 * bx) * 16) * 8192;
  const unsigned short* wb1 = WoB + ((size_t)(2 * bx + 1) * 16) * 8192;

  f32x4 acc[4][4];
  #pragma unroll
  for (int i = 0; i < 4; ++i)
    #pragma unroll
    for (int j = 0; j < 4; ++j) acc[i][j] = (f32x4){0.f, 0.f, 0.f, 0.f};

  for (int kt = 0; kt < 16; ++kt) {
    __syncthreads();
    // A: 2 hi-only blobs, 512 units each.
    #pragma unroll
    for (int s = 0; s < 2; ++s) {
      gload16(oa0 + (size_t)kt * 4096 + (size_t)(s * 256 + tid) * 8,
              &lds[(size_t)(s * 256 + tid) * 8]);
      gload16(oa1 + (size_t)kt * 4096 + (size_t)(s * 256 + tid) * 8,
              &lds[(size_t)(512 + s * 256 + tid) * 8]);
    }
    // B: 2 hi/lo blobs, 1024 units each, at units 1024 and 2048.
    #pragma unroll
    for (int s = 0; s < 4; ++s) {
      gload16(wb0 + (size_t)kt * 8192 + (size_t)(s * 256 + tid) * 8,
              &lds[(size_t)(1024 + s * 256 + tid) * 8]);
      gload16(wb1 + (size_t)kt * 8192 + (size_t)(s * 256 + tid) * 8,
              &lds[(size_t)(2048 + s * 256 + tid) * 8]);
    }
    __syncthreads();
    #pragma unroll
    for (int ch = 0; ch < 2; ++ch) {
      bf16x8 ah[4], bh[4], bl[4];
      #pragma unroll
      for (int f = 0; f < 4; ++f) {
        ah[f] = *(const bf16x8*)&lds[wm * 4096 + FRO(ch, f, lane, 0)];
        bh[f] = *(const bf16x8*)&lds[8192 + wn * 8192 + FRL(0, ch, f, lane, 0)];
        bl[f] = *(const bf16x8*)&lds[8192 + wn * 8192 + FRL(1, ch, f, lane, 0)];
      }
      #pragma unroll
      for (int fm = 0; fm < 4; ++fm)
        #pragma unroll
        for (int fn = 0; fn < 4; ++fn) {
          acc[fm][fn] = MFMA(ah[fm], bh[fn], acc[fm][fn]);
          acc[fm][fn] = MFMA(ah[fm], bl[fn], acc[fm][fn]);
        }
    }
  }

  const int g = lane >> 4, c = lane & 15;
  #pragma unroll
  for (int fm = 0; fm < 4; ++fm)
    #pragma unroll
    for (int fn = 0; fn < 4; ++fn) {
      const int col = 128 * bx + 64 * wn + 16 * fn + c;
      const float bcol = bo[col];
      #pragma unroll
      for (int r = 0; r < 4; ++r) {
        const int row = 128 * by + 64 * wm + 16 * fm + 4 * g + r;
        Y[(size_t)row * DM + col] =
            acc[fm][fn][r] + bcol + X[(size_t)row * DM + col];
      }
    }
}

// ---------------------------------------------------------------------------
// MFMA flash attention v3 (exp2 softmax + P-lo drop + setprio + hi-only O).
// Block = (q-tile 64, head); wave wv owns q-cols 16wv..+15 over all 64 tokens.
// ---------------------------------------------------------------------------
__global__ __launch_bounds__(256) void attn_mfma3_kernel(
    const unsigned short* __restrict__ QF, const unsigned short* __restrict__ KF,
    const unsigned short* __restrict__ VF, unsigned short* __restrict__ OF)
{
  __shared__ __align__(16) unsigned short lds[32768];  // [2 buf][K 8192 | V 8192]

  const int tid = threadIdx.x, lane = tid & 63, wv = tid >> 6;
  const int g = lane >> 4, c = lane & 15;
  const int h = blockIdx.y, tq = blockIdx.x;
  const int q0 = tq * 64;
  const int qq = q0 + 16 * wv + c;

  const unsigned short* qb = QF + ((size_t)h * 32 + tq) * 8192;
  bf16x8 qh[2], ql[2];
  #pragma unroll
  for (int ch = 0; ch < 2; ++ch) {
    qh[ch] = *(const bf16x8*)(qb + FRL(0, ch, wv, lane, 0));
    ql[ch] = *(const bf16x8*)(qb + FRL(1, ch, wv, lane, 0));
  }

  f32x4 acc_o[4];
  #pragma unroll
  for (int df = 0; df < 4; ++df) acc_o[df] = (f32x4){0.f, 0.f, 0.f, 0.f};
  float m_run = -INFINITY, l_run = 0.f;

  const size_t hbase = (size_t)h * 32;
  {
    const unsigned short* kb = KF + hbase * 8192;
    const unsigned short* vb = VF + hbase * 8192;
    #pragma unroll
    for (int s = 0; s < 4; ++s) {
      gload16(kb + (size_t)(s * 256 + tid) * 8, &lds[(size_t)(s * 256 + tid) * 8]);
      gload16(vb + (size_t)(s * 256 + tid) * 8, &lds[8192 + (size_t)(s * 256 + tid) * 8]);
    }
  }

  int buf = 0;
  for (int kt = 0; kt < NTOK / 64; ++kt) {
    __syncthreads();  // drains vmcnt -> buf ready; all waves done with buf^1
    if (kt + 1 < NTOK / 64) {
      const unsigned short* kb = KF + (hbase + kt + 1) * 8192;
      const unsigned short* vb = VF + (hbase + kt + 1) * 8192;
      unsigned short* lk = &lds[(buf ^ 1) * 16384];
      #pragma unroll
      for (int s = 0; s < 4; ++s) {
        gload16(kb + (size_t)(s * 256 + tid) * 8, lk + (size_t)(s * 256 + tid) * 8);
        gload16(vb + (size_t)(s * 256 + tid) * 8, lk + 8192 + (size_t)(s * 256 + tid) * 8);
      }
    }
    const unsigned short* lk = &lds[buf * 16384];
    const unsigned short* lv = lk + 8192;

    // ---- S^T = K * Q^T (split 3-product), logits in log2 domain
    f32x4 sacc[4];
    #pragma unroll
    for (int fm = 0; fm < 4; ++fm) sacc[fm] = (f32x4){0.f, 0.f, 0.f, 0.f};
    __builtin_amdgcn_s_setprio(1);
    #pragma unroll
    for (int ch = 0; ch < 2; ++ch) {
      #pragma unroll
      for (int fm = 0; fm < 4; ++fm) {
        const bf16x8 khf = *(const bf16x8*)&lk[FRL(0, ch, fm, lane, 0)];
        const bf16x8 klf = *(const bf16x8*)&lk[FRL(1, ch, fm, lane, 0)];
        sacc[fm] = MFMA(khf, qh[ch], sacc[fm]);
        sacc[fm] = MFMA(khf, ql[ch], sacc[fm]);
        sacc[fm] = MFMA(klf, qh[ch], sacc[fm]);
      }
    }
    __builtin_amdgcn_s_setprio(0);

    // ---- diagonal mask + online softmax (exp2 domain)
    const int tok0 = kt * 64 + 4 * g;
    #pragma unroll
    for (int fm = 0; fm < 4; ++fm)
      #pragma unroll
      for (int r = 0; r < 4; ++r)
        if (tok0 + 16 * fm + r == qq) sacc[fm][r] = -INFINITY;

    float m = -INFINITY;
    #pragma unroll
    for (int fm = 0; fm < 4; ++fm)
      #pragma unroll
      for (int r = 0; r < 4; ++r) m = fmaxf(m, sacc[fm][r]);
    m = fmaxf(m, __shfl_xor(m, 16, 64));
    m = fmaxf(m, __shfl_xor(m, 32, 64));
    const float mnew = fmaxf(m_run, m);
    const float scal = exp2f(m_run - mnew);    // first tile: exp2(-inf)=0
    float ps = 0.f;
    #pragma unroll
    for (int fm = 0; fm < 4; ++fm)
      #pragma unroll
      for (int r = 0; r < 4; ++r) {
        const float p = exp2f(sacc[fm][r] - mnew);
        sacc[fm][r] = p;
        ps += p;
      }
    ps += __shfl_xor(ps, 16, 64);
    ps += __shfl_xor(ps, 32, 64);
    l_run = l_run * scal + ps;
    m_run = mnew;

    // ---- pack P (hi only; P in [0,1], lo-term ~2^-9 dropped)
    bf16x8 ph[2];
    #pragma unroll
    for (int ch = 0; ch < 2; ++ch)
      #pragma unroll
      for (int i = 0; i < 8; ++i)
        ph[ch][i] = (short)f2bf(sacc[2 * ch + (i >> 2)][i & 3]);

    // ---- rescale + PV: O^T += (Vhi + Vlo) * Phi
    #pragma unroll
    for (int df = 0; df < 4; ++df)
      #pragma unroll
      for (int r = 0; r < 4; ++r) acc_o[df][r] *= scal;
    __builtin_amdgcn_s_setprio(1);
    #pragma unroll
    for (int ch = 0; ch < 2; ++ch)
      #pragma unroll
      for (int df = 0; df < 4; ++df) {
        const bf16x8 vh = *(const bf16x8*)&lv[FRL(0, ch, df, lane, 0)];
        const bf16x8 vl = *(const bf16x8*)&lv[FRL(1, ch, df, lane, 0)];
        acc_o[df] = MFMA(vh, ph[ch], acc_o[df]);
        acc_o[df] = MFMA(vl, ph[ch], acc_o[df]);
      }
    __builtin_amdgcn_s_setprio(0);
    buf ^= 1;
  }

  // ---- epilogue: normalize, scatter hi-only O blob via LDS, copy out
  const float inv = 1.0f / l_run;
  const int n1 = tq >> 4, ktc = tq & 15;
  __syncthreads();                           // all waves done with last tile
  #pragma unroll
  for (int df = 0; df < 4; ++df)
    #pragma unroll
    for (int r = 0; r < 4; ++r) {
      const int d = 16 * df + 4 * g + r;
      const int rw = 2 * d + n1;
      const int rt_l = rw >> 6, row64 = rw & 63;
      const int sti = row64 >> 4, row16 = row64 & 15;
      const int l = 16 * (c >> 2) + row16;
      const int e = 4 * (wv & 1) + (c & 3);
      lds[rt_l * 4096 + FRO(wv >> 1, sti, l, e)] = f2bf(acc_o[df][r] * inv);
    }
  __syncthreads();
  #pragma unroll
  for (int s = 0; s < 2; ++s) {
    const int p = s * 256 + tid;             // 512 used 16B units (parity n1)
    const int rt_l = p >> 8, q = p & 255;
    const int rh = q & 7, gp = (q >> 3) & 3, sti = (q >> 5) & 3, chi = q >> 7;
    const int slot = (chi * 4 + sti) * 64 + 16 * gp + 2 * rh + n1;
    *(uint4*)(OF + (((size_t)(2 * h + rt_l)) * 16 + ktc) * 4096 + (size_t)slot * 8) =
        *(const uint4*)&lds[(size_t)(rt_l * 4096 + slot * 8)];
  }
}

// ---------------------------------------------------------------------------
// LayerNorm (unchanged).
// ---------------------------------------------------------------------------
__global__ __launch_bounds__(256) void ln_kernel(
    const float* __restrict__ Y, const float* __restrict__ g,
    const float* __restrict__ b, float* __restrict__ out)
{
  __shared__ float red[8];
  const int row = blockIdx.x;
  const int tid = threadIdx.x;
  const float4 y = *(const float4*)(Y + (size_t)row * DM + tid * 4);
  float s  = y.x + y.y + y.z + y.w;
  float ss = y.x * y.x + y.y * y.y + y.z * y.z + y.w * y.w;
  #pragma unroll
  for (int o = 1; o < 64; o <<= 1) {
    s  += __shfl_xor(s, o, 64);
    ss += __shfl_xor(ss, o, 64);
  }
  const int wv = tid >> 6;
  if ((tid & 63) == 0) { red[wv] = s; red[4 + wv] = ss; }
  __syncthreads();
  s  = red[0] + red[1] + red[2] + red[3];
  ss = red[4] + red[5] + red[6] + red[7];
  const float mu   = s * (1.f / DM);
  const float var  = ss * (1.f / DM) - mu * mu;
  const float rstd = rsqrtf(var + 1e-5f);
  const float4 gv = *(const float4*)(g + tid * 4);
  const float4 bv = *(const float4*)(b + tid * 4);
  float4 o;
  o.x = (y.x - mu) * rstd * gv.x + bv.x;
  o.y = (y.y - mu) * rstd * gv.y + bv.y;
  o.z = (y.z - mu) * rstd * gv.z + bv.z;
  o.w = (y.w - mu) * rstd * gv.w + bv.w;
  *(float4*)(out + (size_t)row * DM + tid * 4) = o;
}

// ---------------------------------------------------------------------------
extern "C" void kernel_launch(void* const* d_in, const int* in_sizes, int n_in,
                              void* d_out, int out_size, void* d_ws, size_t ws_size,
                              hipStream_t stream) {
  const float* X    = (const float*)d_in[0];
  const float* Wq   = (const float*)d_in[1];
  const float* bq   = (const float*)d_in[2];
  const float* Wk   = (const float*)d_in[3];
  const float* bk   = (const float*)d_in[4];
  const float* Wv   = (const float*)d_in[5];
  const float* bv   = (const float*)d_in[6];
  const float* Wo   = (const float*)d_in[7];
  const float* bo   = (const float*)d_in[8];
  const float* ln_g = (const float*)d_in[9];
  const float* ln_b = (const float*)d_in[10];

  const size_t MAT = (size_t)NTOK * DM;     // 2,097,152
  float* Y = (float*)d_ws;                  // 8 MB
  unsigned short* XB = (unsigned short*)(Y + MAT);  // 2*MAT shorts (8 MB)
  unsigned short* WB = XB + 2 * MAT;        // 4*MAT (16 MB)
  unsigned short* QF = WB + 4 * MAT;        // 2*MAT (8 MB)
  unsigned short* KF = QF + 2 * MAT;        // 2*MAT
  unsigned short* VF = KF + 2 * MAT;        // 2*MAT
  unsigned short* OF = VF + 2 * MAT;        // 1*MAT (4 MB); total 60 MB

  const dim3 blk(256);

  cvt_x_blob<<<dim3(16, 32), blk, 0, stream>>>(X, XB);
  cvt_w_blob<<<dim3(16, 16, 4), blk, 0, stream>>>(Wq, Wk, Wv, Wo, WB);

  gemm_qkv_blob<<<dim3(8, 16, 3), blk, 0, stream>>>(
      XB, WB, bq, bk, bv, QF, KF, VF);

  attn_mfma3_kernel<<<dim3(32, 16), blk, 0, stream>>>(QF, KF, VF, OF);

  gemm_out_blob<<<dim3(8, 16), blk, 0, stream>>>(
      OF, WB + 3 * MAT, bo, X, Y);

  ln_kernel<<<NTOK, blk, 0, stream>>>(Y, ln_g, ln_b, (float*)d_out);
}

// Round 9
// 217.493 us; speedup vs baseline: 1.2929x; 1.0500x over previous
//
#include <hip/hip_runtime.h>
#include <math.h>

// Fused self-attention layer (round 9 = round 8 resubmitted; r8 never ran:
// GPU acquisition timeout. Desk-checked again — no changes).
// r7 diagnosis: attn (78us) is LATENCY-bound: 2 blocks/CU (grid 512/256CU),
// MFMA pipes ~5% busy per-SIMD, long serial chain per k-tile. This round:
// shorten the chain (mask hoisted to the kt==tq tile; defer-max rescale THR=8
// so the acc-rescale leaves the path; truncation P-pack) + drop V-lo (PV 8
// MFMA, LDS 48KB, V blob 8KB, QKV V 2-product) + XCD swizzle (2 heads/XCD ->
// K/V panels L2-resident, FETCH 69.7->~25MB).
//
// Blob format: 64x64 tile, FRL(op,ch,st,lane,e): row = 16*st + (lane&15),
// k = 32*ch + tau(lane>>4,e), tau(g,e) = 4g + (e&3) + 16(e>>2). A and B
// always share tau -> result invariant to the true HW k-map. Hard
// assumptions: C/D col=lane&15,row=(lane>>4)*4+reg [m89/m91]; A/B
// operand-layout symmetry [validated r4/r5/r7 pass].
//
// Workspace (56MB): Y 8MB | XB 8MB | WB 16MB | QF 8MB | KF 8MB | VF 4MB | OF 4MB.

#define NTOK 2048
#define DM   1024
#define NH   16
#define HDIM 64
#define LOG2E 1.4426950408889634f

typedef __attribute__((ext_vector_type(8))) short bf16x8;
typedef __attribute__((ext_vector_type(4))) float f32x4;

// hi/lo blob slot (8192 shorts): [op][ch][st][lane][e]
#define FRL(op, ch, st, l, e) (((((op) * 2 + (ch)) * 4 + (st)) * 64 + (l)) * 8 + (e))
// hi-only blob slot (4096 shorts): [ch][st][lane][e]
#define FRO(ch, st, l, e) ((((ch) * 4 + (st)) * 64 + (l)) * 8 + (e))
#define MFMA(a, b, c) __builtin_amdgcn_mfma_f32_16x16x32_bf16(a, b, c, 0, 0, 0)

__device__ __forceinline__ unsigned short f2bf(float f) {
  unsigned u = __float_as_uint(f);
  u += 0x7FFF + ((u >> 16) & 1);          // RNE
  return (unsigned short)(u >> 16);
}
__device__ __forceinline__ float bf2f(unsigned short h) {
  return __uint_as_float(((unsigned)h) << 16);
}
__device__ __forceinline__ void gload16(const unsigned short* g, unsigned short* l) {
  __builtin_amdgcn_global_load_lds(
      (const __attribute__((address_space(1))) unsigned int*)g,
      (__attribute__((address_space(3))) unsigned int*)l, 16, 0, 0);
}

// ---------------------------------------------------------------------------
// X [2048][1024] fp32 -> hi/lo blobs XB[(rt*16+kt)*8192]. One block per blob.
// ---------------------------------------------------------------------------
__global__ __launch_bounds__(256) void cvt_x_blob(
    const float* __restrict__ X, unsigned short* __restrict__ XB)
{
  __shared__ __align__(16) unsigned short img[8192];
  const int kt = blockIdx.x, rt = blockIdx.y, tid = threadIdx.x;
  #pragma unroll
  for (int s = 0; s < 4; ++s) {
    const int f = tid + s * 256;
    const int rl = f >> 4, c4 = (f & 15) * 4;
    const float4 v = *(const float4*)(X + (size_t)(rt * 64 + rl) * DM + kt * 64 + c4);
    const float vv[4] = {v.x, v.y, v.z, v.w};
    unsigned short hi[4], lo[4];
    #pragma unroll
    for (int e = 0; e < 4; ++e) {
      hi[e] = f2bf(vv[e]);
      lo[e] = f2bf(vv[e] - bf2f(hi[e]));
    }
    const int ch = c4 >> 5, c32 = c4 & 31;
    const int gp = (c32 & 15) >> 2, e0 = (c32 >> 4) * 4;
    const int l = 16 * gp + (rl & 15), sti = rl >> 4;
    *(uint2*)&img[FRL(0, ch, sti, l, e0)] =
        make_uint2(hi[0] | (hi[1] << 16), hi[2] | (hi[3] << 16));
    *(uint2*)&img[FRL(1, ch, sti, l, e0)] =
        make_uint2(lo[0] | (lo[1] << 16), lo[2] | (lo[3] << 16));
  }
  __syncthreads();
  unsigned short* out = XB + ((size_t)rt * 16 + kt) * 8192;
  #pragma unroll
  for (int s = 0; s < 4; ++s) {
    const int u = s * 256 + tid;
    *(uint4*)(out + (size_t)u * 8) = *(const uint4*)&img[(size_t)u * 8];
  }
}

// ---------------------------------------------------------------------------
// W [K][N] fp32 -> transposed hi/lo blobs (rows=n, k=k) at WB + z*2097152.
// ---------------------------------------------------------------------------
__global__ __launch_bounds__(256) void cvt_w_blob(
    const float* __restrict__ W0, const float* __restrict__ W1,
    const float* __restrict__ W2, const float* __restrict__ W3,
    unsigned short* __restrict__ WB)
{
  __shared__ __align__(16) float st[64][68];
  __shared__ __align__(16) unsigned short img[8192];
  const int nt = blockIdx.x, kt = blockIdx.y, z = blockIdx.z, tid = threadIdx.x;
  const float* W = (z == 0) ? W0 : (z == 1) ? W1 : (z == 2) ? W2 : W3;
  #pragma unroll
  for (int s = 0; s < 4; ++s) {
    const int f = tid + s * 256;
    const int kl = f >> 4, n4 = (f & 15) * 4;
    const float4 v = *(const float4*)(W + (size_t)(kt * 64 + kl) * DM + nt * 64 + n4);
    *(float4*)&st[kl][n4] = v;
  }
  __syncthreads();
  #pragma unroll
  for (int s = 0; s < 4; ++s) {
    const int f = tid + s * 256;
    const int nl = f >> 4, k4 = (f & 15) * 4;
    unsigned short hi[4], lo[4];
    #pragma unroll
    for (int e = 0; e < 4; ++e) {
      const float v = st[k4 + e][nl];
      hi[e] = f2bf(v);
      lo[e] = f2bf(v - bf2f(hi[e]));
    }
    const int ch = k4 >> 5, c32 = k4 & 31;
    const int gp = (c32 & 15) >> 2, e0 = (c32 >> 4) * 4;
    const int l = 16 * gp + (nl & 15), sti = nl >> 4;
    *(uint2*)&img[FRL(0, ch, sti, l, e0)] =
        make_uint2(hi[0] | (hi[1] << 16), hi[2] | (hi[3] << 16));
    *(uint2*)&img[FRL(1, ch, sti, l, e0)] =
        make_uint2(lo[0] | (lo[1] << 16), lo[2] | (lo[3] << 16));
  }
  __syncthreads();
  unsigned short* out = WB + (size_t)z * 2097152 + ((size_t)nt * 16 + kt) * 8192;
  #pragma unroll
  for (int s = 0; s < 4; ++s) {
    const int u = s * 256 + tid;
    *(uint4*)(out + (size_t)u * 8) = *(const uint4*)&img[(size_t)u * 8];
  }
}

// ---------------------------------------------------------------------------
// QKV GEMM, 128x128 tile, BK=64, m97 2-barrier loop, split-bf16.
// Q/K: 3-product, hi/lo blobs (token-major; Q pre-scaled by log2e).
// V: 2-product (drops Alo*Bhi), hi-only d-major blobs (feeds PV whose P is
// in [0,1]; error ~2^-9, same order as the hi-only O write downstream).
// ---------------------------------------------------------------------------
__global__ __launch_bounds__(256) void gemm_qkv_blob(
    const unsigned short* __restrict__ XB, const unsigned short* __restrict__ WB,
    const float* __restrict__ bq, const float* __restrict__ bk,
    const float* __restrict__ bv,
    unsigned short* __restrict__ QF, unsigned short* __restrict__ KF,
    unsigned short* __restrict__ VF)
{
  __shared__ __align__(16) unsigned short lds[32768];  // 64KB: A(2 blobs)|B(2 blobs)
  const int tid = threadIdx.x, lane = tid & 63, wid = tid >> 6;
  const int wm = wid >> 1, wn = wid & 1;
  const int bx = blockIdx.x, by = blockIdx.y, z = blockIdx.z;
  const int g = lane >> 4, c = lane & 15;

  const unsigned short* BB = WB + (size_t)z * 2097152;
  const unsigned short* bases[4] = {
      XB + ((size_t)(2 * by) * 16) * 8192, XB + ((size_t)(2 * by + 1) * 16) * 8192,
      BB + ((size_t)(2 * bx) * 16) * 8192, BB + ((size_t)(2 * bx + 1) * 16) * 8192};

  f32x4 acc[4][4];
  #pragma unroll
  for (int i = 0; i < 4; ++i)
    #pragma unroll
    for (int j = 0; j < 4; ++j) acc[i][j] = (f32x4){0.f, 0.f, 0.f, 0.f};

  for (int kt = 0; kt < 16; ++kt) {
    __syncthreads();
    #pragma unroll
    for (int s = 0; s < 16; ++s)
      gload16(bases[s >> 2] + (size_t)kt * 8192 + ((size_t)((s & 3) * 256 + tid)) * 8,
              &lds[(size_t)(s * 256 + tid) * 8]);
    __syncthreads();
    #pragma unroll
    for (int ch = 0; ch < 2; ++ch) {
      bf16x8 ah[4], al[4], bh[4], bl[4];
      #pragma unroll
      for (int f = 0; f < 4; ++f) {
        ah[f] = *(const bf16x8*)&lds[wm * 8192 + FRL(0, ch, f, lane, 0)];
        al[f] = *(const bf16x8*)&lds[wm * 8192 + FRL(1, ch, f, lane, 0)];
        bh[f] = *(const bf16x8*)&lds[16384 + wn * 8192 + FRL(0, ch, f, lane, 0)];
        bl[f] = *(const bf16x8*)&lds[16384 + wn * 8192 + FRL(1, ch, f, lane, 0)];
      }
      #pragma unroll
      for (int fm = 0; fm < 4; ++fm)
        #pragma unroll
        for (int fn = 0; fn < 4; ++fn) {
          acc[fm][fn] = MFMA(ah[fm], bh[fn], acc[fm][fn]);
          acc[fm][fn] = MFMA(ah[fm], bl[fn], acc[fm][fn]);
          if (z != 2)  // V: 2-product suffices (hi-only consumer)
            acc[fm][fn] = MFMA(al[fm], bh[fn], acc[fm][fn]);
        }
    }
  }

  const float* bias = (z == 0) ? bq : (z == 1) ? bk : bv;

  __syncthreads();                         // main-loop LDS reads complete
  if (z != 2) {                            // ---- Q/K: hi/lo token-major blobs
    unsigned short* OUTF = (z == 0) ? QF : KF;
    const int imgb = (wm * 2 + wn) * 8192;
    #pragma unroll
    for (int fm = 0; fm < 4; ++fm)
      #pragma unroll
      for (int fn = 0; fn < 4; ++fn) {
        const int col = 128 * bx + 64 * wn + 16 * fn + c;
        const float bcol = bias[col];
        #pragma unroll
        for (int r = 0; r < 4; ++r) {
          float val = acc[fm][fn][r] + bcol;
          if (z == 0) val *= LOG2E;        // exp2-domain softmax
          const unsigned short hp = f2bf(val);
          const unsigned short lp = f2bf(val - bf2f(hp));
          const int sti = fm, l = 16 * (c >> 2) + (4 * g + r);
          const int ch_i = fn >> 1, e = 4 * (fn & 1) + (c & 3);
          lds[imgb + FRL(0, ch_i, sti, l, e)] = hp;
          lds[imgb + FRL(1, ch_i, sti, l, e)] = lp;
        }
      }
    __syncthreads();
    #pragma unroll
    for (int s = 0; s < 16; ++s) {
      const int u = s * 256 + tid;
      const int i = s >> 2;                // image quadrant (wm_i*2 + wn_i)
      const int head = 2 * bx + (i & 1), tt = 2 * by + (i >> 1);
      *(uint4*)(OUTF + ((size_t)head * 32 + tt) * 8192 + (size_t)(u & 1023) * 8) =
          *(const uint4*)&lds[(size_t)u * 8];
    }
  } else {                                 // ---- V: hi-only d-major blobs
    const int imgb = (wm * 2 + wn) * 4096;
    #pragma unroll
    for (int fm = 0; fm < 4; ++fm)
      #pragma unroll
      for (int fn = 0; fn < 4; ++fn) {
        const int col = 128 * bx + 64 * wn + 16 * fn + c;
        const float bcol = bias[col];
        #pragma unroll
        for (int r = 0; r < 4; ++r) {
          const float val = acc[fm][fn][r] + bcol;
          const int sti = fn, l = 16 * g + c;
          const int ch_i = fm >> 1, e = 4 * (fm & 1) + r;
          lds[imgb + FRO(ch_i, sti, l, e)] = f2bf(val);
        }
      }
    __syncthreads();
    #pragma unroll
    for (int s = 0; s < 8; ++s) {
      const int u = s * 256 + tid;         // 2048 16B units
      const int i = u >> 9;                // quadrant
      const int head = 2 * bx + (i & 1), tt = 2 * by + (i >> 1);
      *(uint4*)(VF + ((size_t)head * 32 + tt) * 4096 + (size_t)(u & 511) * 8) =
          *(const uint4*)&lds[(size_t)u * 8];
    }
  }
}

// ---------------------------------------------------------------------------
// Out-proj GEMM: Y = O @ Wo + bo + X. A = hi-only O blobs (2-product),
// B = Wo hi/lo blobs. 128x128 tile, BK=64.
// LDS unit map (16B): A0 [0,512) | A1 [512,1024) | B0 [1024,2048) | B1 [2048,3072).
// ---------------------------------------------------------------------------
__global__ __launch_bounds__(256) void gemm_out_blob(
    const unsigned short* __restrict__ OF, const unsigned short* __restrict__ WoB,
    const float* __restrict__ bo, const float* __restrict__ X,
    float* __restrict__ Y)
{
  __shared__ __align__(16) unsigned short lds[24576];  // 48KB
  const int tid = threadIdx.x, lane = tid & 63, wid = tid >> 6;
  const int wm = wid >> 1, wn = wid & 1;
  const int bx = blockIdx.x, by = blockIdx.y;

  const unsigned short* oa0 = OF + ((size_t)(2 * by) * 16) * 4096;
  const unsigned short* oa1 = OF + ((size_t)(2 * by + 1) * 16) * 4096;
  const unsigned short* wb0 = WoB + ((size_t)(2 * bx) * 16) * 8192;
  const unsigned short* wb1 = WoB + ((size_t)(2 * bx + 1) * 16) * 8192;

  f32x4 acc[4][4];
  #pragma unroll
  for (int i = 0; i < 4; ++i)
    #pragma unroll
    for (int j = 0; j < 4; ++j) acc[i][j] = (f32x4){0.f, 0.f, 0.f, 0.f};

  for (int kt = 0; kt < 16; ++kt) {
    __syncthreads();
    #pragma unroll
    for (int s = 0; s < 2; ++s) {
      gload16(oa0 + (size_t)kt * 4096 + (size_t)(s * 256 + tid) * 8,
              &lds[(size_t)(s * 256 + tid) * 8]);
      gload16(oa1 + (size_t)kt * 4096 + (size_t)(s * 256 + tid) * 8,
              &lds[(size_t)(512 + s * 256 + tid) * 8]);
    }
    #pragma unroll
    for (int s = 0; s < 4; ++s) {
      gload16(wb0 + (size_t)kt * 8192 + (size_t)(s * 256 + tid) * 8,
              &lds[(size_t)(1024 + s * 256 + tid) * 8]);
      gload16(wb1 + (size_t)kt * 8192 + (size_t)(s * 256 + tid) * 8,
              &lds[(size_t)(2048 + s * 256 + tid) * 8]);
    }
    __syncthreads();
    #pragma unroll
    for (int ch = 0; ch < 2; ++ch) {
      bf16x8 ah[4], bh[4], bl[4];
      #pragma unroll
      for (int f = 0; f < 4; ++f) {
        ah[f] = *(const bf16x8*)&lds[wm * 4096 + FRO(ch, f, lane, 0)];
        bh[f] = *(const bf16x8*)&lds[8192 + wn * 8192 + FRL(0, ch, f, lane, 0)];
        bl[f] = *(const bf16x8*)&lds[8192 + wn * 8192 + FRL(1, ch, f, lane, 0)];
      }
      #pragma unroll
      for (int fm = 0; fm < 4; ++fm)
        #pragma unroll
        for (int fn = 0; fn < 4; ++fn) {
          acc[fm][fn] = MFMA(ah[fm], bh[fn], acc[fm][fn]);
          acc[fm][fn] = MFMA(ah[fm], bl[fn], acc[fm][fn]);
        }
    }
  }

  const int g = lane >> 4, c = lane & 15;
  #pragma unroll
  for (int fm = 0; fm < 4; ++fm)
    #pragma unroll
    for (int fn = 0; fn < 4; ++fn) {
      const int col = 128 * bx + 64 * wn + 16 * fn + c;
      const float bcol = bo[col];
      #pragma unroll
      for (int r = 0; r < 4; ++r) {
        const int row = 128 * by + 64 * wm + 16 * fm + 4 * g + r;
        Y[(size_t)row * DM + col] =
            acc[fm][fn][r] + bcol + X[(size_t)row * DM + col];
      }
    }
}

// ---------------------------------------------------------------------------
// MFMA flash attention v4: latency-bound fixes. XCD swizzle (2 heads/XCD),
// mask hoisted to kt==tq, defer-max rescale (THR=8 log2), truncation P-pack,
// V hi-only (PV single product, 8 MFMA), LDS 48KB dbuf.
// ---------------------------------------------------------------------------
__global__ __launch_bounds__(256) void attn_mfma4_kernel(
    const unsigned short* __restrict__ QF, const unsigned short* __restrict__ KF,
    const unsigned short* __restrict__ VF, unsigned short* __restrict__ OF)
{
  __shared__ __align__(16) unsigned short lds[24576];  // [2 buf][K 8192 | V 4096]

  const int tid = threadIdx.x, lane = tid & 63, wv = tid >> 6;
  const int g = lane >> 4, c = lane & 15;
  // XCD-aware remap: dispatch-order id -> (h, tq) so each XCD owns 2 heads.
  const int flat = blockIdx.y * gridDim.x + blockIdx.x;   // 0..511
  const int o = (flat & 7) * 64 + (flat >> 3);
  const int h = o >> 5, tq = o & 31;
  const int q0 = tq * 64;
  const int qq = q0 + 16 * wv + c;

  const unsigned short* qb = QF + ((size_t)h * 32 + tq) * 8192;
  bf16x8 qh[2], ql[2];
  #pragma unroll
  for (int ch = 0; ch < 2; ++ch) {
    qh[ch] = *(const bf16x8*)(qb + FRL(0, ch, wv, lane, 0));
    ql[ch] = *(const bf16x8*)(qb + FRL(1, ch, wv, lane, 0));
  }

  f32x4 acc_o[4];
  #pragma unroll
  for (int df = 0; df < 4; ++df) acc_o[df] = (f32x4){0.f, 0.f, 0.f, 0.f};
  float m_run = -INFINITY, l_run = 0.f;

  const size_t hbase = (size_t)h * 32;
  {
    const unsigned short* kb = KF + hbase * 8192;
    const unsigned short* vb = VF + hbase * 4096;
    #pragma unroll
    for (int s = 0; s < 4; ++s)
      gload16(kb + (size_t)(s * 256 + tid) * 8, &lds[(size_t)(s * 256 + tid) * 8]);
    #pragma unroll
    for (int s = 0; s < 2; ++s)
      gload16(vb + (size_t)(s * 256 + tid) * 8, &lds[8192 + (size_t)(s * 256 + tid) * 8]);
  }

  int buf = 0;
  for (int kt = 0; kt < NTOK / 64; ++kt) {
    __syncthreads();  // drains vmcnt -> buf ready; all waves done with buf^1
    if (kt + 1 < NTOK / 64) {
      const unsigned short* kb = KF + (hbase + kt + 1) * 8192;
      const unsigned short* vb = VF + (hbase + kt + 1) * 4096;
      unsigned short* lk = &lds[(buf ^ 1) * 12288];
      #pragma unroll
      for (int s = 0; s < 4; ++s)
        gload16(kb + (size_t)(s * 256 + tid) * 8, lk + (size_t)(s * 256 + tid) * 8);
      #pragma unroll
      for (int s = 0; s < 2; ++s)
        gload16(vb + (size_t)(s * 256 + tid) * 8, lk + 8192 + (size_t)(s * 256 + tid) * 8);
    }
    const unsigned short* lk = &lds[buf * 12288];
    const unsigned short* lv = lk + 8192;

    // ---- S^T = K * Q^T (split 3-product), logits in log2 domain
    f32x4 sacc[4];
    #pragma unroll
    for (int fm = 0; fm < 4; ++fm) sacc[fm] = (f32x4){0.f, 0.f, 0.f, 0.f};
    __builtin_amdgcn_s_setprio(1);
    #pragma unroll
    for (int ch = 0; ch < 2; ++ch) {
      #pragma unroll
      for (int fm = 0; fm < 4; ++fm) {
        const bf16x8 khf = *(const bf16x8*)&lk[FRL(0, ch, fm, lane, 0)];
        const bf16x8 klf = *(const bf16x8*)&lk[FRL(1, ch, fm, lane, 0)];
        sacc[fm] = MFMA(khf, qh[ch], sacc[fm]);
        sacc[fm] = MFMA(khf, ql[ch], sacc[fm]);
        sacc[fm] = MFMA(klf, qh[ch], sacc[fm]);
      }
    }
    __builtin_amdgcn_s_setprio(0);

    // ---- diagonal mask: only the kt==tq tile intersects the diagonal
    if (kt == tq) {
      const int tok0 = kt * 64 + 4 * g;
      #pragma unroll
      for (int fm = 0; fm < 4; ++fm)
        #pragma unroll
        for (int r = 0; r < 4; ++r)
          if (tok0 + 16 * fm + r == qq) sacc[fm][r] = -INFINITY;
    }

    // ---- online softmax (exp2 domain), defer-max with THR=8
    float m = -INFINITY;
    #pragma unroll
    for (int fm = 0; fm < 4; ++fm)
      #pragma unroll
      for (int r = 0; r < 4; ++r) m = fmaxf(m, sacc[fm][r]);
    m = fmaxf(m, __shfl_xor(m, 16, 64));
    m = fmaxf(m, __shfl_xor(m, 32, 64));
    if (__any(m > m_run + 8.0f)) {         // rare after tile 0
      const float mnew = fmaxf(m_run, m);
      const float scal = exp2f(m_run - mnew);  // first tile: 0
      l_run *= scal;
      #pragma unroll
      for (int df = 0; df < 4; ++df)
        #pragma unroll
        for (int r = 0; r < 4; ++r) acc_o[df][r] *= scal;
      m_run = mnew;
    }
    float ps = 0.f;
    #pragma unroll
    for (int fm = 0; fm < 4; ++fm)
      #pragma unroll
      for (int r = 0; r < 4; ++r) {
        const float p = exp2f(sacc[fm][r] - m_run);  // bounded by 2^8
        sacc[fm][r] = p;
        ps += p;
      }
    ps += __shfl_xor(ps, 16, 64);
    ps += __shfl_xor(ps, 32, 64);
    l_run += ps;

    // ---- pack P (hi only, truncation; P in [0,256])
    bf16x8 ph[2];
    #pragma unroll
    for (int ch = 0; ch < 2; ++ch)
      #pragma unroll
      for (int i = 0; i < 8; ++i)
        ph[ch][i] = (short)(__float_as_uint(sacc[2 * ch + (i >> 2)][i & 3]) >> 16);

    // ---- PV: O^T += Vhi * Phi (single product)
    __builtin_amdgcn_s_setprio(1);
    #pragma unroll
    for (int ch = 0; ch < 2; ++ch)
      #pragma unroll
      for (int df = 0; df < 4; ++df) {
        const bf16x8 vh = *(const bf16x8*)&lv[FRO(ch, df, lane, 0)];
        acc_o[df] = MFMA(vh, ph[ch], acc_o[df]);
      }
    __builtin_amdgcn_s_setprio(0);
    buf ^= 1;
  }

  // ---- epilogue: normalize, scatter hi-only O blob via LDS, copy out
  const float inv = 1.0f / l_run;
  const int n1 = tq >> 4, ktc = tq & 15;
  __syncthreads();                           // all waves done with last tile
  #pragma unroll
  for (int df = 0; df < 4; ++df)
    #pragma unroll
    for (int r = 0; r < 4; ++r) {
      const int d = 16 * df + 4 * g + r;
      const int rw = 2 * d + n1;
      const int rt_l = rw >> 6, row64 = rw & 63;
      const int sti = row64 >> 4, row16 = row64 & 15;
      const int l = 16 * (c >> 2) + row16;
      const int e = 4 * (wv & 1) + (c & 3);
      lds[rt_l * 4096 + FRO(wv >> 1, sti, l, e)] = f2bf(acc_o[df][r] * inv);
    }
  __syncthreads();
  #pragma unroll
  for (int s = 0; s < 2; ++s) {
    const int p = s * 256 + tid;             // 512 used 16B units (parity n1)
    const int rt_l = p >> 8, q = p & 255;
    const int rh = q & 7, gp = (q >> 3) & 3, sti = (q >> 5) & 3, chi = q >> 7;
    const int slot = (chi * 4 + sti) * 64 + 16 * gp + 2 * rh + n1;
    *(uint4*)(OF + (((size_t)(2 * h + rt_l)) * 16 + ktc) * 4096 + (size_t)slot * 8) =
        *(const uint4*)&lds[(size_t)(rt_l * 4096 + slot * 8)];
  }
}

// ---------------------------------------------------------------------------
// LayerNorm (unchanged).
// ---------------------------------------------------------------------------
__global__ __launch_bounds__(256) void ln_kernel(
    const float* __restrict__ Y, const float* __restrict__ g,
    const float* __restrict__ b, float* __restrict__ out)
{
  __shared__ float red[8];
  const int row = blockIdx.x;
  const int tid = threadIdx.x;
  const float4 y = *(const float4*)(Y + (size_t)row * DM + tid * 4);
  float s  = y.x + y.y + y.z + y.w;
  float ss = y.x * y.x + y.y * y.y + y.z * y.z + y.w * y.w;
  #pragma unroll
  for (int o = 1; o < 64; o <<= 1) {
    s  += __shfl_xor(s, o, 64);
    ss += __shfl_xor(ss, o, 64);
  }
  const int wv = tid >> 6;
  if ((tid & 63) == 0) { red[wv] = s; red[4 + wv] = ss; }
  __syncthreads();
  s  = red[0] + red[1] + red[2] + red[3];
  ss = red[4] + red[5] + red[6] + red[7];
  const float mu   = s * (1.f / DM);
  const float var  = ss * (1.f / DM) - mu * mu;
  const float rstd = rsqrtf(var + 1e-5f);
  const float4 gv = *(const float4*)(g + tid * 4);
  const float4 bv = *(const float4*)(b + tid * 4);
  float4 o;
  o.x = (y.x - mu) * rstd * gv.x + bv.x;
  o.y = (y.y - mu) * rstd * gv.y + bv.y;
  o.z = (y.z - mu) * rstd * gv.z + bv.z;
  o.w = (y.w - mu) * rstd * gv.w + bv.w;
  *(float4*)(out + (size_t)row * DM + tid * 4) = o;
}

// ---------------------------------------------------------------------------
extern "C" void kernel_launch(void* const* d_in, const int* in_sizes, int n_in,
                              void* d_out, int out_size, void* d_ws, size_t ws_size,
                              hipStream_t stream) {
  const float* X    = (const float*)d_in[0];
  const float* Wq   = (const float*)d_in[1];
  const float* bq   = (const float*)d_in[2];
  const float* Wk   = (const float*)d_in[3];
  const float* bk   = (const float*)d_in[4];
  const float* Wv   = (const float*)d_in[5];
  const float* bv   = (const float*)d_in[6];
  const float* Wo   = (const float*)d_in[7];
  const float* bo   = (const float*)d_in[8];
  const float* ln_g = (const float*)d_in[9];
  const float* ln_b = (const float*)d_in[10];

  const size_t MAT = (size_t)NTOK * DM;     // 2,097,152
  float* Y = (float*)d_ws;                  // 8 MB
  unsigned short* XB = (unsigned short*)(Y + MAT);  // 2*MAT shorts (8 MB)
  unsigned short* WB = XB + 2 * MAT;        // 4*MAT (16 MB)
  unsigned short* QF = WB + 4 * MAT;        // 2*MAT (8 MB)
  unsigned short* KF = QF + 2 * MAT;        // 2*MAT (8 MB)
  unsigned short* VF = KF + 2 * MAT;        // 1*MAT (4 MB, hi-only)
  unsigned short* OF = VF + MAT;            // 1*MAT (4 MB); total 56 MB

  const dim3 blk(256);

  cvt_x_blob<<<dim3(16, 32), blk, 0, stream>>>(X, XB);
  cvt_w_blob<<<dim3(16, 16, 4), blk, 0, stream>>>(Wq, Wk, Wv, Wo, WB);

  gemm_qkv_blob<<<dim3(8, 16, 3), blk, 0, stream>>>(
      XB, WB, bq, bk, bv, QF, KF, VF);

  attn_mfma4_kernel<<<dim3(32, 16), blk, 0, stream>>>(QF, KF, VF, OF);

  gemm_out_blob<<<dim3(8, 16), blk, 0, stream>>>(
      OF, WB + 3 * MAT, bo, X, Y);

  ln_kernel<<<NTOK, blk, 0, stream>>>(Y, ln_g, ln_b, (float*)d_out);
}